// Round 9
// baseline (3684.710 us; speedup 1.0000x reference)
//
#include <hip/hip_runtime.h>
#include <hip/hip_bf16.h>
#include <cstddef>
#include <math.h>

#define kB 32
#define kN1 4096
#define kS1 512
#define kNS1 32
#define kS2 128
#define kNS2 64

// Launder a value through a VGPR so the compiler cannot prove wave-uniformity.
// Forces weight loads onto the VMEM path (global_load, vmcnt-pipelined) instead
// of SMEM s_load (out-of-order -> lgkmcnt(0) drains, serializing with LDS reads).
#define OPAQUE_V(x) asm("" : "+v"(x))

// ---------------- fused weight folding for all 9 layers ----------------
struct FoldDesc {
  const float *W, *b, *g, *bt;
  float *Wout, *bout;
  int O, K, Kp, transposed;
};
struct FoldPack {
  FoldDesc d[9];
  int cum[10];
};

__global__ __launch_bounds__(256) void foldall_kernel(FoldPack p) {
  int blk = blockIdx.x;
  int L = 0;
#pragma unroll
  for (int i = 0; i < 9; ++i)
    if (blk >= p.cum[i + 1]) L = i + 1;
  FoldDesc d = p.d[L];
  int nb = p.cum[L + 1] - p.cum[L];
  int tid = (blk - p.cum[L]) * 256 + threadIdx.x;
  int stride = nb * 256;
  float inv = 1.0f / sqrtf(1.0f + 1e-5f);
  for (int i = tid; i < d.O * d.Kp; i += stride) {
    int o = i / d.Kp, k = i - o * d.Kp;
    float s = d.g[o] * inv;
    float w = (k < d.K) ? d.W[o * d.K + k] * s : 0.0f;
    if (d.transposed) d.Wout[k * d.O + o] = w;
    else d.Wout[o * d.Kp + k] = w;
  }
  for (int o = tid; o < d.O; o += stride) {
    d.bout[o] = d.b[o] * (d.g[o] * inv) + d.bt[o];
  }
}

// ---------------- farthest point sampling ----------------
// Coords in LDS as float4 groups (12 ds_read_b128/thread/iter); dd state (16
// floats, named float4s) register-resident. f32 butterfly reduce + ballot;
// exact first-index tie-break via rare wave-uniform readlane fallback.
// Cross-wave winner slots keep the exact u64 key {dist_bits<<32 | ~idx}.
#define FPS_E(V, C, XV, YV, ZV, I)                                           \
  {                                                                          \
    float dx = __fsub_rn((XV), cx);                                          \
    float dy = __fsub_rn((YV), cy);                                          \
    float dz = __fsub_rn((ZV), cz);                                          \
    float d = fmaf(dz, dz, fmaf(dy, dy, __fmul_rn(dx, dx)));                 \
    float nd = fminf(dd##V.C, d);                                            \
    dd##V.C = nd;                                                            \
    if (nd > bestf) { bestf = nd; besti = (I); bx = (XV); by = (YV); bz = (ZV); } \
  }

#define FPS_GRP(V, R)                                                        \
  {                                                                          \
    float4 xg = sx4[t + (R) * T];                                            \
    float4 yg = sy4[t + (R) * T];                                            \
    float4 zg = sz4[t + (R) * T];                                            \
    int ibase = 4 * (t + (R) * T);                                           \
    FPS_E(V, x, xg.x, yg.x, zg.x, ibase)                                     \
    FPS_E(V, y, xg.y, yg.y, zg.y, ibase + 1)                                 \
    FPS_E(V, z, xg.z, yg.z, zg.z, ibase + 2)                                 \
    FPS_E(V, w, xg.w, yg.w, zg.w, ibase + 3)                                 \
  }

template <int N, int NP, int T>
__global__ __launch_bounds__(T, 1) void fps16_kernel(const float* __restrict__ xyz,
                                                     float* __restrict__ nx) {
  static_assert(N == 16 * T, "fps16: need exactly 16 points per thread");
  constexpr int W = T / 64;
  __shared__ float4 sx4[N / 4], sy4[N / 4], sz4[N / 4];
  __shared__ float4 sslot[2][W][2];
  __shared__ int fid[NP];
  int b = blockIdx.x, t = threadIdx.x;
  int w = t >> 6;
  const float* base = xyz + (size_t)b * 3 * N;
  float* sxf = (float*)sx4;
  float* syf = (float*)sy4;
  float* szf = (float*)sz4;
  for (int i = t; i < N; i += T) sxf[i] = base[i];
  for (int i = t; i < N; i += T) syf[i] = base[N + i];
  for (int i = t; i < N; i += T) szf[i] = base[2 * N + i];
  float4 dd0, dd1, dd2, dd3;
  dd0 = dd1 = dd2 = dd3 = make_float4(1e10f, 1e10f, 1e10f, 1e10f);
  if (t == 0) {
    fid[0] = 0;
    unsigned long long k0 = ~0ull;  // decodes to idx 0; max key so slot 0 wins iter 1
    sslot[0][0][0] = make_float4(__uint_as_float((unsigned)k0),
                                 __uint_as_float((unsigned)(k0 >> 32)),
                                 base[0], base[N]);
    sslot[0][0][1] = make_float4(base[2 * N], 0.0f, 0.0f, 0.0f);
  }
  if (t >= 64 && (t & 63) == 0) {
    sslot[0][w][0] = make_float4(0.0f, 0.0f, 0.0f, 0.0f);
    sslot[0][w][1] = make_float4(0.0f, 0.0f, 0.0f, 0.0f);
  }
  int par = 0;
  __syncthreads();
  for (int it = 1; it < NP; ++it) {
    float4 q0 = sslot[par][0][0];
    float4 q1 = sslot[par][0][1];
    unsigned long long mk =
        ((unsigned long long)__float_as_uint(q0.y) << 32) | __float_as_uint(q0.x);
    float cx = q0.z, cy = q0.w, cz = q1.x;
#pragma unroll
    for (int w2 = 1; w2 < W; ++w2) {
      float4 p0 = sslot[par][w2][0];
      float4 p1 = sslot[par][w2][1];
      unsigned long long k2 =
          ((unsigned long long)__float_as_uint(p0.y) << 32) | __float_as_uint(p0.x);
      if (k2 > mk) { mk = k2; cx = p0.z; cy = p0.w; cz = p1.x; }
    }
    if (t == 0) fid[it - 1] = (int)(~(unsigned)mk);
    float bestf = -1.0f;
    int besti = 4 * t;
    float bx = 0.0f, by = 0.0f, bz = 0.0f;
    FPS_GRP(0, 0)
    FPS_GRP(1, 1)
    FPS_GRP(2, 2)
    FPS_GRP(3, 3)
    // f32 wave max + ballot; exact first-index tie-break on the rare tie
    float wmax = bestf;
#pragma unroll
    for (int off = 1; off <= 32; off <<= 1)
      wmax = fmaxf(wmax, __shfl_xor(wmax, off, 64));
    unsigned long long m = __ballot(bestf == wmax);
    bool pub;
    if (__popcll(m) == 1) {
      pub = (bestf == wmax);
    } else {
      unsigned long long mm = m;
      int bidx = 0x7fffffff;
      while (mm) {
        int l = __ffsll(mm) - 1;
        int bi = __shfl(besti, l, 64);
        bidx = min(bidx, bi);
        mm &= mm - 1;
      }
      pub = (besti == bidx);
    }
    if (pub) {
      unsigned long long key =
          ((unsigned long long)__float_as_uint(wmax) << 32) | (unsigned)(~besti);
      sslot[par ^ 1][w][0] = make_float4(__uint_as_float((unsigned)key),
                                         __uint_as_float((unsigned)(key >> 32)), bx, by);
      sslot[par ^ 1][w][1] = make_float4(bz, 0.0f, 0.0f, 0.0f);
    }
    __syncthreads();
    par ^= 1;
  }
  {
    float4 q0 = sslot[par][0][0];
    unsigned long long mk =
        ((unsigned long long)__float_as_uint(q0.y) << 32) | __float_as_uint(q0.x);
#pragma unroll
    for (int w2 = 1; w2 < W; ++w2) {
      float4 p0 = sslot[par][w2][0];
      unsigned long long k2 =
          ((unsigned long long)__float_as_uint(p0.y) << 32) | __float_as_uint(p0.x);
      if (k2 > mk) mk = k2;
    }
    if (t == 0) fid[NP - 1] = (int)(~(unsigned)mk);
  }
  __syncthreads();
  for (int s = t; s < NP; s += T) {
    int f = fid[s];
    nx[(size_t)b * 3 * NP + s] = sxf[f];
    nx[(size_t)b * 3 * NP + NP + s] = syf[f];
    nx[(size_t)b * 3 * NP + 2 * NP + s] = szf[f];
  }
}

// fps4: R=4 register-resident variant (fps2: N=512, T=128). Proven VGPR=20 shape.
#define FPS_STEP(V, C, IDXOFF)                                               \
  {                                                                          \
    float dx = __fsub_rn(px##V.C, cx);                                       \
    float dy = __fsub_rn(py##V.C, cy);                                       \
    float dz = __fsub_rn(pz##V.C, cz);                                       \
    float d = fmaf(dz, dz, fmaf(dy, dy, __fmul_rn(dx, dx)));                 \
    float nd = fminf(dd##V.C, d);                                            \
    dd##V.C = nd;                                                            \
    if (nd > bestf) {                                                        \
      bestf = nd; besti = t + (IDXOFF); bx = px##V.C; by = py##V.C; bz = pz##V.C; \
    }                                                                        \
  }

#define FPS_LD4(arr, src, off) \
  arr = make_float4((src)[(off)], (src)[(off) + T], (src)[(off) + 2 * T], (src)[(off) + 3 * T])

template <int N, int NP, int T>
__global__ __launch_bounds__(T, 1) void fps4_kernel(const float* __restrict__ xyz,
                                                    float* __restrict__ nx) {
  static_assert(N == 4 * T, "fps4: need exactly 4 points per thread");
  constexpr int W = T / 64;
  __shared__ float4 sslot[2][W][2];
  __shared__ int fid[NP];
  int b = blockIdx.x, t = threadIdx.x;
  int w = t >> 6;
  const float* base = xyz + (size_t)b * 3 * N;
  float4 px0, py0, pz0, dd0;
  FPS_LD4(px0, base, t);
  FPS_LD4(py0, base + N, t);
  FPS_LD4(pz0, base + 2 * N, t);
  dd0 = make_float4(1e10f, 1e10f, 1e10f, 1e10f);
  if (t == 0) {
    fid[0] = 0;
    unsigned long long k0 = ~0ull;
    sslot[0][0][0] = make_float4(__uint_as_float((unsigned)k0),
                                 __uint_as_float((unsigned)(k0 >> 32)), px0.x, py0.x);
    sslot[0][0][1] = make_float4(pz0.x, 0.0f, 0.0f, 0.0f);
  }
  if (t >= 64 && (t & 63) == 0) {
    sslot[0][w][0] = make_float4(0.0f, 0.0f, 0.0f, 0.0f);
    sslot[0][w][1] = make_float4(0.0f, 0.0f, 0.0f, 0.0f);
  }
  int par = 0;
  __syncthreads();
  for (int it = 1; it < NP; ++it) {
    float4 q0 = sslot[par][0][0];
    float4 q1 = sslot[par][0][1];
    unsigned long long mk =
        ((unsigned long long)__float_as_uint(q0.y) << 32) | __float_as_uint(q0.x);
    float cx = q0.z, cy = q0.w, cz = q1.x;
#pragma unroll
    for (int w2 = 1; w2 < W; ++w2) {
      float4 p0 = sslot[par][w2][0];
      float4 p1 = sslot[par][w2][1];
      unsigned long long k2 =
          ((unsigned long long)__float_as_uint(p0.y) << 32) | __float_as_uint(p0.x);
      if (k2 > mk) { mk = k2; cx = p0.z; cy = p0.w; cz = p1.x; }
    }
    if (t == 0) fid[it - 1] = (int)(~(unsigned)mk);
    float bestf = -1.0f;
    int besti = t;
    float bx = px0.x, by = py0.x, bz = pz0.x;
    FPS_STEP(0, x, 0) FPS_STEP(0, y, T) FPS_STEP(0, z, 2 * T) FPS_STEP(0, w, 3 * T)
    unsigned long long lbest =
        ((unsigned long long)__float_as_uint(bestf) << 32) | (unsigned)(~besti);
    unsigned long long wbest = lbest;
#pragma unroll
    for (int off = 1; off <= 32; off <<= 1) {
      unsigned long long o = __shfl_xor(wbest, off, 64);
      if (o > wbest) wbest = o;
    }
    if (lbest == wbest) {
      sslot[par ^ 1][w][0] = make_float4(__uint_as_float((unsigned)wbest),
                                         __uint_as_float((unsigned)(wbest >> 32)), bx, by);
      sslot[par ^ 1][w][1] = make_float4(bz, 0.0f, 0.0f, 0.0f);
    }
    __syncthreads();
    par ^= 1;
  }
  {
    float4 q0 = sslot[par][0][0];
    unsigned long long mk =
        ((unsigned long long)__float_as_uint(q0.y) << 32) | __float_as_uint(q0.x);
#pragma unroll
    for (int w2 = 1; w2 < W; ++w2) {
      float4 p0 = sslot[par][w2][0];
      unsigned long long k2 =
          ((unsigned long long)__float_as_uint(p0.y) << 32) | __float_as_uint(p0.x);
      if (k2 > mk) mk = k2;
    }
    if (t == 0) fid[NP - 1] = (int)(~(unsigned)mk);
  }
  __syncthreads();
  for (int s = t; s < NP; s += T) {
    int f = fid[s];
    nx[(size_t)b * 3 * NP + s] = base[f];
    nx[(size_t)b * 3 * NP + NP + s] = base[N + f];
    nx[(size_t)b * 3 * NP + 2 * NP + s] = base[2 * N + f];
  }
}

// ---------------- ball query ----------------
template <int NPTS, int NQ, int NS>
__global__ void bq_kernel(const float* __restrict__ pts, const float* __restrict__ qry,
                          float r2, int* __restrict__ gidx) {
  int gw = (blockIdx.x * blockDim.x + threadIdx.x) >> 6;
  int lane = threadIdx.x & 63;
  if (gw >= kB * NQ) return;
  int b = gw / NQ, s = gw - b * NQ;
  const float* pb = pts + (size_t)b * 3 * NPTS;
  float cx = qry[(size_t)b * 3 * NQ + s];
  float cy = qry[(size_t)b * 3 * NQ + NQ + s];
  float cz = qry[(size_t)b * 3 * NQ + 2 * NQ + s];
  float ss = fmaf(cz, cz, fmaf(cy, cy, __fmul_rn(cx, cx)));
  int* out = gidx + (size_t)gw * NS;
  int have = 0, first = 0;
  bool gotfirst = false;
  for (int n0 = 0; n0 < NPTS; n0 += 64) {
    int n = n0 + lane;
    float x = pb[n], y = pb[NPTS + n], z = pb[2 * NPTS + n];
    float dd = fmaf(z, z, fmaf(y, y, __fmul_rn(x, x)));
    float cross = fmaf(cz, z, fmaf(cy, y, __fmul_rn(cx, x)));
    float sqr = __fsub_rn(__fadd_rn(ss, dd), __fmul_rn(2.0f, cross));
    bool pred = !(sqr > r2);
    unsigned long long mask = __ballot(pred);
    if (!gotfirst && mask) { first = n0 + (__ffsll(mask) - 1); gotfirst = true; }
    if (pred) {
      int pos = have + __popcll(mask & ((1ull << lane) - 1ull));
      if (pos < NS) out[pos] = n;
    }
    have += __popcll(mask);
    if (have >= NS) break;
  }
  for (int slot = have + lane; slot < NS; slot += 64) out[slot] = first;
}

// ---------------- SA1 grouped MLP (3->64->64->128) + max over 32 samples ----------------
// LDS-capped at 2 blocks/CU (64KB XT) -> launch_bounds(256,2) frees the VGPR cap
// for the in-flight VMEM weight row (opaque-VGPR addressing).
__global__ __launch_bounds__(256, 2) void sa1_mlp_kernel(
    const float* __restrict__ xyz, const float* __restrict__ nx1,
    const int* __restrict__ gidx,
    const float* __restrict__ W0f, const float* __restrict__ bf0,   // [64][4], [64]
    const float* __restrict__ WT1, const float* __restrict__ bf1,   // [64][64]
    const float* __restrict__ WT2, const float* __restrict__ bf2,   // [64][128]
    float* __restrict__ l1_pts) {
  __shared__ float XT[64 * 256];   // reused for X1 then X2
  int t = threadIdx.x;
  int qi = t >> 5, sm = t & 31;
  int q = blockIdx.x * 8 + qi;
  int b = q >> 9, s = q & 511;
  int idx = gidx[(size_t)q * kNS1 + sm];
  float cx = nx1[b * 1536 + s];
  float cy = nx1[b * 1536 + 512 + s];
  float cz = nx1[b * 1536 + 1024 + s];
  const float* pb = xyz + (size_t)b * 3 * kN1;
  float f0 = pb[idx] - cx, f1 = pb[kN1 + idx] - cy, f2 = pb[2 * kN1 + idx] - cz;
  int zofs = 0;
  OPAQUE_V(zofs);   // force VMEM weight loads (see macro comment)
  for (int j = 0; j < 64; ++j) {
    float4 w = *(const float4*)&W0f[j * 4];
    float v = fmaf(f2, w.z, fmaf(f1, w.y, fmaf(f0, w.x, bf0[j])));
    XT[j * 256 + t] = fmaxf(v, 0.0f);
  }
  __syncthreads();
  float acc[64];
#pragma unroll
  for (int j = 0; j < 64; ++j) acc[j] = bf1[j];
  for (int k = 0; k < 64; ++k) {
    float xk = XT[k * 256 + t];
    const float* wr = WT1 + k * 64 + zofs;
#pragma unroll
    for (int j = 0; j < 64; ++j) acc[j] = fmaf(xk, wr[j], acc[j]);
  }
  __syncthreads();
#pragma unroll
  for (int j = 0; j < 64; ++j) XT[j * 256 + t] = fmaxf(acc[j], 0.0f);
  __syncthreads();
  float* outp = l1_pts + (size_t)q * 128;
  for (int jp = 0; jp < 2; ++jp) {
#pragma unroll
    for (int j = 0; j < 64; ++j) acc[j] = bf2[jp * 64 + j];
    for (int k = 0; k < 64; ++k) {
      float xk = XT[k * 256 + t];
      const float* wr = WT2 + k * 128 + jp * 64 + zofs;
#pragma unroll
      for (int j = 0; j < 64; ++j) acc[j] = fmaf(xk, wr[j], acc[j]);
    }
#pragma unroll
    for (int j = 0; j < 64; ++j) {
      float m = fmaxf(acc[j], 0.0f);
      m = fmaxf(m, __shfl_xor(m, 1, 64));
      m = fmaxf(m, __shfl_xor(m, 2, 64));
      m = fmaxf(m, __shfl_xor(m, 4, 64));
      m = fmaxf(m, __shfl_xor(m, 8, 64));
      m = fmaxf(m, __shfl_xor(m, 16, 64));
      if (sm == 0) outp[jp * 64 + j] = m;
    }
  }
}

// ---------------- SA2 grouped MLP (131->128->128->256) + max over 64 samples ----------------
#define F_STR 133
__global__ __launch_bounds__(256, 4) void sa2_mlp_kernel(
    const float* __restrict__ nx1, const float* __restrict__ l1_pts,
    const float* __restrict__ nx2, const int* __restrict__ gidx2,
    const float* __restrict__ WT1, const float* __restrict__ bf1,   // [132][128]
    const float* __restrict__ WT2, const float* __restrict__ bf2,   // [128][128]
    const float* __restrict__ WT3, const float* __restrict__ bf3,   // [128][256]
    float* __restrict__ l2_pts) {
  __shared__ float fb[64 * F_STR];
  int t = threadIdx.x;
  int lane = t & 63;
  int wg = t >> 6;
  int q = blockIdx.x;
  int b = q >> 7, s = q & 127;
  int idx = gidx2[(size_t)q * kNS2 + lane];
  const float* pr = l1_pts + ((size_t)(b * kS1) + idx) * 128;
  float* frow = fb + lane * F_STR;
#pragma unroll
  for (int i = 0; i < 8; ++i) {
    float4 v = *(const float4*)&pr[wg * 32 + i * 4];
    frow[3 + wg * 32 + i * 4 + 0] = v.x;
    frow[3 + wg * 32 + i * 4 + 1] = v.y;
    frow[3 + wg * 32 + i * 4 + 2] = v.z;
    frow[3 + wg * 32 + i * 4 + 3] = v.w;
  }
  if (wg == 0) {
    float cx = nx2[b * 384 + s];
    float cy = nx2[b * 384 + 128 + s];
    float cz = nx2[b * 384 + 256 + s];
    frow[0] = nx1[b * 1536 + idx] - cx;
    frow[1] = nx1[b * 1536 + 512 + idx] - cy;
    frow[2] = nx1[b * 1536 + 1024 + idx] - cz;
    frow[131] = 0.0f;
  }
  int jofs = wg * 32;
  OPAQUE_V(jofs);   // force VMEM weight loads (see macro comment)
  __syncthreads();
  float acc[32];
#pragma unroll
  for (int j = 0; j < 32; ++j) acc[j] = bf1[wg * 32 + j];
#pragma unroll 2
  for (int k = 0; k < 132; ++k) {
    float xk = frow[k];
    const float* wr = WT1 + k * 128 + jofs;
#pragma unroll
    for (int j = 0; j < 32; ++j) acc[j] = fmaf(xk, wr[j], acc[j]);
  }
  __syncthreads();
#pragma unroll
  for (int j = 0; j < 32; ++j) frow[wg * 32 + j] = fmaxf(acc[j], 0.0f);
  __syncthreads();
#pragma unroll
  for (int j = 0; j < 32; ++j) acc[j] = bf2[wg * 32 + j];
#pragma unroll 2
  for (int k = 0; k < 128; ++k) {
    float xk = frow[k];
    const float* wr = WT2 + k * 128 + jofs;
#pragma unroll
    for (int j = 0; j < 32; ++j) acc[j] = fmaf(xk, wr[j], acc[j]);
  }
  __syncthreads();
#pragma unroll
  for (int j = 0; j < 32; ++j) frow[wg * 32 + j] = fmaxf(acc[j], 0.0f);
  __syncthreads();
  float* outp = l2_pts + (size_t)q * 256;
  for (int jp = 0; jp < 2; ++jp) {
    int j0 = wg * 64 + jp * 32;
    int j0v = j0;
    OPAQUE_V(j0v);
#pragma unroll
    for (int j = 0; j < 32; ++j) acc[j] = bf3[j0 + j];
#pragma unroll 2
    for (int k = 0; k < 128; ++k) {
      float xk = frow[k];
      const float* wr = WT3 + k * 256 + j0v;
#pragma unroll
      for (int j = 0; j < 32; ++j) acc[j] = fmaf(xk, wr[j], acc[j]);
    }
#pragma unroll
    for (int j = 0; j < 32; ++j) {
      float m = fmaxf(acc[j], 0.0f);
      m = fmaxf(m, __shfl_xor(m, 1, 64));
      m = fmaxf(m, __shfl_xor(m, 2, 64));
      m = fmaxf(m, __shfl_xor(m, 4, 64));
      m = fmaxf(m, __shfl_xor(m, 8, 64));
      m = fmaxf(m, __shfl_xor(m, 16, 64));
      m = fmaxf(m, __shfl_xor(m, 32, 64));
      if (lane == 0) outp[j0 + j] = m;
    }
  }
}

// ---------------- SA3 (group-all): 259->256->512->1024 -> max over 128 ----------------
__global__ __launch_bounds__(256, 2) void sa3_passA_kernel(
    const float* __restrict__ nx2, const float* __restrict__ l2_pts,
    const float* __restrict__ WT, const float* __restrict__ bf,
    float* __restrict__ Y) {   // O = 256
  __shared__ float sF[16 * 260];
  int stile = blockIdx.x, t = threadIdx.x;
  int j = t;
  for (int i = t; i < 16 * 260; i += 256) {
    int row = stile * 16 + i / 260, k = i - (i / 260) * 260;
    int b = row >> 7, s = row & 127;
    float v;
    if (k < 3) v = nx2[b * 384 + k * 128 + s];
    else if (k < 259) v = l2_pts[(size_t)row * 256 + (k - 3)];
    else v = 0.0f;
    sF[i] = v;
  }
  __syncthreads();
  float acc[16];
  float bj = bf[j];
#pragma unroll
  for (int s = 0; s < 16; ++s) acc[s] = bj;
  for (int k = 0; k < 260; k += 4) {
    float w0 = WT[(size_t)k * 256 + j];
    float w1 = WT[(size_t)(k + 1) * 256 + j];
    float w2 = WT[(size_t)(k + 2) * 256 + j];
    float w3 = WT[(size_t)(k + 3) * 256 + j];
#pragma unroll
    for (int s = 0; s < 16; ++s) {
      const float4 fv = *(const float4*)&sF[s * 260 + k];
      acc[s] = fmaf(fv.x, w0, acc[s]);
      acc[s] = fmaf(fv.y, w1, acc[s]);
      acc[s] = fmaf(fv.z, w2, acc[s]);
      acc[s] = fmaf(fv.w, w3, acc[s]);
    }
  }
  float* yb = Y + (size_t)stile * 16 * 256 + j;
#pragma unroll
  for (int s = 0; s < 16; ++s) yb[(size_t)s * 256] = fmaxf(acc[s], 0.0f);
}

template <int KP>
__global__ __launch_bounds__(256, 2) void mlp_pass_kernel(
    const float* __restrict__ X, const float* __restrict__ WT, const float* __restrict__ bf,
    int O, float* __restrict__ Y) {
  __shared__ float sF[16 * KP];
  int stile = blockIdx.x, t = threadIdx.x;
  int j = blockIdx.y * 256 + t;
  const float* xb = X + (size_t)stile * 16 * KP;
  for (int i = t; i < 16 * KP; i += 256) sF[i] = xb[i];
  __syncthreads();
  float acc[16];
  float bj = bf[j];
#pragma unroll
  for (int s = 0; s < 16; ++s) acc[s] = bj;
  for (int k = 0; k < KP; k += 4) {
    float w0 = WT[(size_t)k * O + j];
    float w1 = WT[(size_t)(k + 1) * O + j];
    float w2 = WT[(size_t)(k + 2) * O + j];
    float w3 = WT[(size_t)(k + 3) * O + j];
#pragma unroll
    for (int s = 0; s < 16; ++s) {
      const float4 fv = *(const float4*)&sF[s * KP + k];
      acc[s] = fmaf(fv.x, w0, acc[s]);
      acc[s] = fmaf(fv.y, w1, acc[s]);
      acc[s] = fmaf(fv.z, w2, acc[s]);
      acc[s] = fmaf(fv.w, w3, acc[s]);
    }
  }
  float* yb = Y + (size_t)stile * 16 * O + j;
#pragma unroll
  for (int s = 0; s < 16; ++s) yb[(size_t)s * O] = fmaxf(acc[s], 0.0f);
}

__global__ __launch_bounds__(256, 2) void sa3_final_kernel(
    const float* __restrict__ X2g, const float* __restrict__ WTc, const float* __restrict__ bfc,
    float* __restrict__ out) {
  __shared__ float sF[16 * 512];
  int b = blockIdx.x, t = threadIdx.x;
  int j = blockIdx.y * 256 + t;
  float m = 0.0f;
  float bj = bfc[j];
  for (int st = 0; st < 8; ++st) {
    const float* xb = X2g + ((size_t)b * 128 + st * 16) * 512;
    for (int i = t; i < 16 * 512; i += 256) sF[i] = xb[i];
    __syncthreads();
    float acc[16];
#pragma unroll
    for (int s = 0; s < 16; ++s) acc[s] = bj;
    for (int k = 0; k < 512; k += 4) {
      float w0 = WTc[(size_t)k * 1024 + j];
      float w1 = WTc[(size_t)(k + 1) * 1024 + j];
      float w2 = WTc[(size_t)(k + 2) * 1024 + j];
      float w3 = WTc[(size_t)(k + 3) * 1024 + j];
#pragma unroll
      for (int s = 0; s < 16; ++s) {
        const float4 fv = *(const float4*)&sF[s * 512 + k];
        acc[s] = fmaf(fv.x, w0, acc[s]);
        acc[s] = fmaf(fv.y, w1, acc[s]);
        acc[s] = fmaf(fv.z, w2, acc[s]);
        acc[s] = fmaf(fv.w, w3, acc[s]);
      }
    }
#pragma unroll
    for (int s = 0; s < 16; ++s) m = fmaxf(m, fmaxf(acc[s], 0.0f));
    __syncthreads();
  }
  out[(size_t)b * 1024 + j] = m;
}

// ---------------- launch ----------------
extern "C" void kernel_launch(void* const* d_in, const int* in_sizes, int n_in,
                              void* d_out, int out_size, void* d_ws, size_t ws_size,
                              hipStream_t stream) {
  (void)in_sizes; (void)n_in; (void)out_size; (void)ws_size;
  const float* xyz = (const float*)d_in[0];
  auto WP = [&](int layer, int part) -> const float* {
    return (const float*)d_in[1 + layer * 4 + part];
  };
  float* wsf = (float*)d_ws;
  size_t cur = 0;
  auto alloc = [&](size_t n) { size_t o = cur; cur += (n + 63) & ~(size_t)63; return o; };
  size_t o_nx1 = alloc((size_t)kB * 3 * kS1);
  size_t o_nx2 = alloc((size_t)kB * 3 * kS2);
  size_t o_l1pts = alloc((size_t)kB * kS1 * 128);
  size_t o_l2pts = alloc((size_t)kB * kS2 * 256);
  size_t o_X1g = alloc((size_t)kB * kS2 * 256);
  size_t o_X2g = alloc((size_t)kB * kS2 * 512);
  size_t o_s1w0 = alloc(64 * 4), o_s1b0 = alloc(64);
  size_t o_s1w1 = alloc(64 * 64), o_s1b1 = alloc(64);
  size_t o_s1wt2 = alloc(64 * 128), o_s1b2 = alloc(128);
  size_t o_s2w1 = alloc(132 * 128), o_s2b1 = alloc(128);
  size_t o_s2wt2 = alloc(128 * 128), o_s2b2 = alloc(128);
  size_t o_s2w3 = alloc(128 * 256), o_s2b3 = alloc(256);
  size_t o_s3wtA = alloc(260 * 256), o_s3bA = alloc(256);
  size_t o_s3wtB = alloc(256 * 512), o_s3bB = alloc(512);
  size_t o_s3wtC = alloc(512 * 1024), o_s3bC = alloc(1024);
  size_t o_gidx1 = alloc((size_t)kB * kS1 * kNS1);
  size_t o_gidx2 = alloc((size_t)kB * kS2 * kNS2);
  int* gidx1 = (int*)(wsf + o_gidx1);
  int* gidx2 = (int*)(wsf + o_gidx2);

  // fused fold of all 9 layers
  FoldPack fp;
  const int OKKp[9][3] = {{64, 3, 4},     {64, 64, 64},   {128, 64, 64},
                          {128, 131, 132}, {128, 128, 128}, {256, 128, 128},
                          {256, 259, 260}, {512, 256, 256}, {1024, 512, 512}};
  float* wouts[9] = {wsf + o_s1w0, wsf + o_s1w1, wsf + o_s1wt2,
                     wsf + o_s2w1, wsf + o_s2wt2, wsf + o_s2w3,
                     wsf + o_s3wtA, wsf + o_s3wtB, wsf + o_s3wtC};
  float* bouts[9] = {wsf + o_s1b0, wsf + o_s1b1, wsf + o_s1b2,
                     wsf + o_s2b1, wsf + o_s2b2, wsf + o_s2b3,
                     wsf + o_s3bA, wsf + o_s3bB, wsf + o_s3bC};
  const int nblk[9] = {1, 4, 8, 17, 16, 32, 65, 128, 512};
  fp.cum[0] = 0;
  for (int L = 0; L < 9; ++L) {
    fp.d[L].W = WP(L, 0);
    fp.d[L].b = WP(L, 1);
    fp.d[L].g = WP(L, 2);
    fp.d[L].bt = WP(L, 3);
    fp.d[L].Wout = wouts[L];
    fp.d[L].bout = bouts[L];
    fp.d[L].O = OKKp[L][0];
    fp.d[L].K = OKKp[L][1];
    fp.d[L].Kp = OKKp[L][2];
    fp.d[L].transposed = (L == 0) ? 0 : 1;
    fp.cum[L + 1] = fp.cum[L] + nblk[L];
  }
  foldall_kernel<<<fp.cum[9], 256, 0, stream>>>(fp);

  // SA1
  fps16_kernel<kN1, kS1, 256><<<kB, 256, 0, stream>>>(xyz, wsf + o_nx1);
  bq_kernel<kN1, kS1, kNS1><<<(kB * kS1) / 4, 256, 0, stream>>>(xyz, wsf + o_nx1, 0.04f, gidx1);
  sa1_mlp_kernel<<<(kB * kS1) / 8, 256, 0, stream>>>(
      xyz, wsf + o_nx1, gidx1,
      wsf + o_s1w0, wsf + o_s1b0, wsf + o_s1w1, wsf + o_s1b1, wsf + o_s1wt2, wsf + o_s1b2,
      wsf + o_l1pts);

  // SA2
  fps4_kernel<kS1, kS2, 128><<<kB, 128, 0, stream>>>(wsf + o_nx1, wsf + o_nx2);
  bq_kernel<kS1, kS2, kNS2><<<(kB * kS2) / 4, 256, 0, stream>>>(wsf + o_nx1, wsf + o_nx2, 0.16f, gidx2);
  sa2_mlp_kernel<<<kB * kS2, 256, 0, stream>>>(
      wsf + o_nx1, wsf + o_l1pts, wsf + o_nx2, gidx2,
      wsf + o_s2w1, wsf + o_s2b1, wsf + o_s2wt2, wsf + o_s2b2, wsf + o_s2w3, wsf + o_s2b3,
      wsf + o_l2pts);

  // SA3 (group all)
  sa3_passA_kernel<<<256, 256, 0, stream>>>(wsf + o_nx2, wsf + o_l2pts,
                                            wsf + o_s3wtA, wsf + o_s3bA, wsf + o_X1g);
  mlp_pass_kernel<256><<<dim3(256, 2), 256, 0, stream>>>(wsf + o_X1g, wsf + o_s3wtB, wsf + o_s3bB, 512, wsf + o_X2g);
  sa3_final_kernel<<<dim3(kB, 4), 256, 0, stream>>>(wsf + o_X2g, wsf + o_s3wtC, wsf + o_s3bC, (float*)d_out);
}

// Round 10
// 1809.932 us; speedup vs baseline: 2.0358x; 2.0358x over previous
//
#include <hip/hip_runtime.h>
#include <hip/hip_bf16.h>
#include <cstddef>
#include <math.h>

#define kB 32
#define kN1 4096
#define kS1 512
#define kNS1 32
#define kS2 128
#define kNS2 64

// ---------------- fused weight folding for all 9 layers ----------------
struct FoldDesc {
  const float *W, *b, *g, *bt;
  float *Wout, *bout;
  int O, K, Kp, transposed;
};
struct FoldPack {
  FoldDesc d[9];
  int cum[10];
};

__global__ __launch_bounds__(256) void foldall_kernel(FoldPack p) {
  int blk = blockIdx.x;
  int L = 0;
#pragma unroll
  for (int i = 0; i < 9; ++i)
    if (blk >= p.cum[i + 1]) L = i + 1;
  FoldDesc d = p.d[L];
  int nb = p.cum[L + 1] - p.cum[L];
  int tid = (blk - p.cum[L]) * 256 + threadIdx.x;
  int stride = nb * 256;
  float inv = 1.0f / sqrtf(1.0f + 1e-5f);
  for (int i = tid; i < d.O * d.Kp; i += stride) {
    int o = i / d.Kp, k = i - o * d.Kp;
    float s = d.g[o] * inv;
    float w = (k < d.K) ? d.W[o * d.K + k] * s : 0.0f;
    if (d.transposed) d.Wout[k * d.O + o] = w;
    else d.Wout[o * d.Kp + k] = w;
  }
  for (int o = tid; o < d.O; o += stride) {
    d.bout[o] = d.b[o] * (d.g[o] * inv) + d.bt[o];
  }
}

// ---------------- farthest point sampling ----------------
// Coords in LDS as float4 groups (12 ds_read_b128/thread/iter); dd state (16
// floats, named float4s) register-resident. One barrier/iter. Winner slot
// {u64 key = dist_bits<<32 | ~idx, cx, cy, cz} in 2 float4s per wave; key
// gives exact first-max (lowest index) tie-break.
#define FPS_E(V, C, XV, YV, ZV, I)                                           \
  {                                                                          \
    float dx = __fsub_rn((XV), cx);                                          \
    float dy = __fsub_rn((YV), cy);                                          \
    float dz = __fsub_rn((ZV), cz);                                          \
    float d = fmaf(dz, dz, fmaf(dy, dy, __fmul_rn(dx, dx)));                 \
    float nd = fminf(dd##V.C, d);                                            \
    dd##V.C = nd;                                                            \
    if (nd > bestf) { bestf = nd; besti = (I); bx = (XV); by = (YV); bz = (ZV); } \
  }

#define FPS_GRP(V, R)                                                        \
  {                                                                          \
    float4 xg = sx4[t + (R) * T];                                            \
    float4 yg = sy4[t + (R) * T];                                            \
    float4 zg = sz4[t + (R) * T];                                            \
    int ibase = 4 * (t + (R) * T);                                           \
    FPS_E(V, x, xg.x, yg.x, zg.x, ibase)                                     \
    FPS_E(V, y, xg.y, yg.y, zg.y, ibase + 1)                                 \
    FPS_E(V, z, xg.z, yg.z, zg.z, ibase + 2)                                 \
    FPS_E(V, w, xg.w, yg.w, zg.w, ibase + 3)                                 \
  }

template <int N, int NP, int T>
__global__ __launch_bounds__(T, 1) void fps16_kernel(const float* __restrict__ xyz,
                                                     float* __restrict__ nx) {
  static_assert(N == 16 * T, "fps16: need exactly 16 points per thread");
  constexpr int W = T / 64;
  __shared__ float4 sx4[N / 4], sy4[N / 4], sz4[N / 4];
  __shared__ float4 sslot[2][W][2];
  __shared__ int fid[NP];
  int b = blockIdx.x, t = threadIdx.x;
  int w = t >> 6;
  const float* base = xyz + (size_t)b * 3 * N;
  float* sxf = (float*)sx4;
  float* syf = (float*)sy4;
  float* szf = (float*)sz4;
  for (int i = t; i < N; i += T) sxf[i] = base[i];
  for (int i = t; i < N; i += T) syf[i] = base[N + i];
  for (int i = t; i < N; i += T) szf[i] = base[2 * N + i];
  float4 dd0, dd1, dd2, dd3;
  dd0 = dd1 = dd2 = dd3 = make_float4(1e10f, 1e10f, 1e10f, 1e10f);
  if (t == 0) {
    fid[0] = 0;
    unsigned long long k0 = ~0ull;  // decodes to idx 0; max key so slot 0 wins iter 1
    sslot[0][0][0] = make_float4(__uint_as_float((unsigned)k0),
                                 __uint_as_float((unsigned)(k0 >> 32)),
                                 base[0], base[N]);
    sslot[0][0][1] = make_float4(base[2 * N], 0.0f, 0.0f, 0.0f);
  }
  if (t >= 64 && (t & 63) == 0) {
    sslot[0][w][0] = make_float4(0.0f, 0.0f, 0.0f, 0.0f);
    sslot[0][w][1] = make_float4(0.0f, 0.0f, 0.0f, 0.0f);
  }
  int par = 0;
  __syncthreads();
  for (int it = 1; it < NP; ++it) {
    float4 q0 = sslot[par][0][0];
    float4 q1 = sslot[par][0][1];
    unsigned long long mk =
        ((unsigned long long)__float_as_uint(q0.y) << 32) | __float_as_uint(q0.x);
    float cx = q0.z, cy = q0.w, cz = q1.x;
#pragma unroll
    for (int w2 = 1; w2 < W; ++w2) {
      float4 p0 = sslot[par][w2][0];
      float4 p1 = sslot[par][w2][1];
      unsigned long long k2 =
          ((unsigned long long)__float_as_uint(p0.y) << 32) | __float_as_uint(p0.x);
      if (k2 > mk) { mk = k2; cx = p0.z; cy = p0.w; cz = p1.x; }
    }
    if (t == 0) fid[it - 1] = (int)(~(unsigned)mk);
    float bestf = -1.0f;
    int besti = 4 * t;
    float bx = 0.0f, by = 0.0f, bz = 0.0f;
    FPS_GRP(0, 0)
    FPS_GRP(1, 1)
    FPS_GRP(2, 2)
    FPS_GRP(3, 3)
    unsigned long long lbest =
        ((unsigned long long)__float_as_uint(bestf) << 32) | (unsigned)(~besti);
    unsigned long long wbest = lbest;
#pragma unroll
    for (int off = 1; off <= 32; off <<= 1) {
      unsigned long long o = __shfl_xor(wbest, off, 64);
      if (o > wbest) wbest = o;
    }
    if (lbest == wbest) {  // unique winner lane publishes key+coords
      sslot[par ^ 1][w][0] = make_float4(__uint_as_float((unsigned)wbest),
                                         __uint_as_float((unsigned)(wbest >> 32)), bx, by);
      sslot[par ^ 1][w][1] = make_float4(bz, 0.0f, 0.0f, 0.0f);
    }
    __syncthreads();
    par ^= 1;
  }
  {
    float4 q0 = sslot[par][0][0];
    unsigned long long mk =
        ((unsigned long long)__float_as_uint(q0.y) << 32) | __float_as_uint(q0.x);
#pragma unroll
    for (int w2 = 1; w2 < W; ++w2) {
      float4 p0 = sslot[par][w2][0];
      unsigned long long k2 =
          ((unsigned long long)__float_as_uint(p0.y) << 32) | __float_as_uint(p0.x);
      if (k2 > mk) mk = k2;
    }
    if (t == 0) fid[NP - 1] = (int)(~(unsigned)mk);
  }
  __syncthreads();
  for (int s = t; s < NP; s += T) {
    int f = fid[s];
    nx[(size_t)b * 3 * NP + s] = sxf[f];
    nx[(size_t)b * 3 * NP + NP + s] = syf[f];
    nx[(size_t)b * 3 * NP + 2 * NP + s] = szf[f];
  }
}

// fps4: R=4 register-resident variant (fps2: N=512, T=128). Proven VGPR=20 shape.
#define FPS_STEP(V, C, IDXOFF)                                               \
  {                                                                          \
    float dx = __fsub_rn(px##V.C, cx);                                       \
    float dy = __fsub_rn(py##V.C, cy);                                       \
    float dz = __fsub_rn(pz##V.C, cz);                                       \
    float d = fmaf(dz, dz, fmaf(dy, dy, __fmul_rn(dx, dx)));                 \
    float nd = fminf(dd##V.C, d);                                            \
    dd##V.C = nd;                                                            \
    if (nd > bestf) {                                                        \
      bestf = nd; besti = t + (IDXOFF); bx = px##V.C; by = py##V.C; bz = pz##V.C; \
    }                                                                        \
  }

#define FPS_LD4(arr, src, off) \
  arr = make_float4((src)[(off)], (src)[(off) + T], (src)[(off) + 2 * T], (src)[(off) + 3 * T])

template <int N, int NP, int T>
__global__ __launch_bounds__(T, 1) void fps4_kernel(const float* __restrict__ xyz,
                                                    float* __restrict__ nx) {
  static_assert(N == 4 * T, "fps4: need exactly 4 points per thread");
  constexpr int W = T / 64;
  __shared__ float4 sslot[2][W][2];
  __shared__ int fid[NP];
  int b = blockIdx.x, t = threadIdx.x;
  int w = t >> 6;
  const float* base = xyz + (size_t)b * 3 * N;
  float4 px0, py0, pz0, dd0;
  FPS_LD4(px0, base, t);
  FPS_LD4(py0, base + N, t);
  FPS_LD4(pz0, base + 2 * N, t);
  dd0 = make_float4(1e10f, 1e10f, 1e10f, 1e10f);
  if (t == 0) {
    fid[0] = 0;
    unsigned long long k0 = ~0ull;
    sslot[0][0][0] = make_float4(__uint_as_float((unsigned)k0),
                                 __uint_as_float((unsigned)(k0 >> 32)), px0.x, py0.x);
    sslot[0][0][1] = make_float4(pz0.x, 0.0f, 0.0f, 0.0f);
  }
  if (t >= 64 && (t & 63) == 0) {
    sslot[0][w][0] = make_float4(0.0f, 0.0f, 0.0f, 0.0f);
    sslot[0][w][1] = make_float4(0.0f, 0.0f, 0.0f, 0.0f);
  }
  int par = 0;
  __syncthreads();
  for (int it = 1; it < NP; ++it) {
    float4 q0 = sslot[par][0][0];
    float4 q1 = sslot[par][0][1];
    unsigned long long mk =
        ((unsigned long long)__float_as_uint(q0.y) << 32) | __float_as_uint(q0.x);
    float cx = q0.z, cy = q0.w, cz = q1.x;
#pragma unroll
    for (int w2 = 1; w2 < W; ++w2) {
      float4 p0 = sslot[par][w2][0];
      float4 p1 = sslot[par][w2][1];
      unsigned long long k2 =
          ((unsigned long long)__float_as_uint(p0.y) << 32) | __float_as_uint(p0.x);
      if (k2 > mk) { mk = k2; cx = p0.z; cy = p0.w; cz = p1.x; }
    }
    if (t == 0) fid[it - 1] = (int)(~(unsigned)mk);
    float bestf = -1.0f;
    int besti = t;
    float bx = px0.x, by = py0.x, bz = pz0.x;
    FPS_STEP(0, x, 0) FPS_STEP(0, y, T) FPS_STEP(0, z, 2 * T) FPS_STEP(0, w, 3 * T)
    unsigned long long lbest =
        ((unsigned long long)__float_as_uint(bestf) << 32) | (unsigned)(~besti);
    unsigned long long wbest = lbest;
#pragma unroll
    for (int off = 1; off <= 32; off <<= 1) {
      unsigned long long o = __shfl_xor(wbest, off, 64);
      if (o > wbest) wbest = o;
    }
    if (lbest == wbest) {
      sslot[par ^ 1][w][0] = make_float4(__uint_as_float((unsigned)wbest),
                                         __uint_as_float((unsigned)(wbest >> 32)), bx, by);
      sslot[par ^ 1][w][1] = make_float4(bz, 0.0f, 0.0f, 0.0f);
    }
    __syncthreads();
    par ^= 1;
  }
  {
    float4 q0 = sslot[par][0][0];
    unsigned long long mk =
        ((unsigned long long)__float_as_uint(q0.y) << 32) | __float_as_uint(q0.x);
#pragma unroll
    for (int w2 = 1; w2 < W; ++w2) {
      float4 p0 = sslot[par][w2][0];
      unsigned long long k2 =
          ((unsigned long long)__float_as_uint(p0.y) << 32) | __float_as_uint(p0.x);
      if (k2 > mk) mk = k2;
    }
    if (t == 0) fid[NP - 1] = (int)(~(unsigned)mk);
  }
  __syncthreads();
  for (int s = t; s < NP; s += T) {
    int f = fid[s];
    nx[(size_t)b * 3 * NP + s] = base[f];
    nx[(size_t)b * 3 * NP + NP + s] = base[N + f];
    nx[(size_t)b * 3 * NP + 2 * NP + s] = base[2 * N + f];
  }
}

// ---------------- ball query ----------------
template <int NPTS, int NQ, int NS>
__global__ void bq_kernel(const float* __restrict__ pts, const float* __restrict__ qry,
                          float r2, int* __restrict__ gidx) {
  int gw = (blockIdx.x * blockDim.x + threadIdx.x) >> 6;
  int lane = threadIdx.x & 63;
  if (gw >= kB * NQ) return;
  int b = gw / NQ, s = gw - b * NQ;
  const float* pb = pts + (size_t)b * 3 * NPTS;
  float cx = qry[(size_t)b * 3 * NQ + s];
  float cy = qry[(size_t)b * 3 * NQ + NQ + s];
  float cz = qry[(size_t)b * 3 * NQ + 2 * NQ + s];
  float ss = fmaf(cz, cz, fmaf(cy, cy, __fmul_rn(cx, cx)));
  int* out = gidx + (size_t)gw * NS;
  int have = 0, first = 0;
  bool gotfirst = false;
  for (int n0 = 0; n0 < NPTS; n0 += 64) {
    int n = n0 + lane;
    float x = pb[n], y = pb[NPTS + n], z = pb[2 * NPTS + n];
    float dd = fmaf(z, z, fmaf(y, y, __fmul_rn(x, x)));
    float cross = fmaf(cz, z, fmaf(cy, y, __fmul_rn(cx, x)));
    float sqr = __fsub_rn(__fadd_rn(ss, dd), __fmul_rn(2.0f, cross));
    bool pred = !(sqr > r2);
    unsigned long long mask = __ballot(pred);
    if (!gotfirst && mask) { first = n0 + (__ffsll(mask) - 1); gotfirst = true; }
    if (pred) {
      int pos = have + __popcll(mask & ((1ull << lane) - 1ull));
      if (pos < NS) out[pos] = n;
    }
    have += __popcll(mask);
    if (have >= NS) break;
  }
  for (int slot = have + lane; slot < NS; slot += 64) out[slot] = first;
}

// ---------------- SA1 grouped MLP (3->64->64->128) + max over 32 samples ----------------
// SGPR weight path: wr pointers are block-uniform -> s_load; weights feed fmas
// as SGPR operands (free). LDS 64KB -> 2 blocks/CU.
__global__ __launch_bounds__(256, 2) void sa1_mlp_kernel(
    const float* __restrict__ xyz, const float* __restrict__ nx1,
    const int* __restrict__ gidx,
    const float* __restrict__ W0f, const float* __restrict__ bf0,   // [64][4], [64]
    const float* __restrict__ WT1, const float* __restrict__ bf1,   // [64][64]
    const float* __restrict__ WT2, const float* __restrict__ bf2,   // [64][128]
    float* __restrict__ l1_pts) {
  __shared__ float XT[64 * 256];   // reused for X1 then X2
  int t = threadIdx.x;
  int qi = t >> 5, sm = t & 31;
  int q = blockIdx.x * 8 + qi;
  int b = q >> 9, s = q & 511;
  int idx = gidx[(size_t)q * kNS1 + sm];
  float cx = nx1[b * 1536 + s];
  float cy = nx1[b * 1536 + 512 + s];
  float cz = nx1[b * 1536 + 1024 + s];
  const float* pb = xyz + (size_t)b * 3 * kN1;
  float f0 = pb[idx] - cx, f1 = pb[kN1 + idx] - cy, f2 = pb[2 * kN1 + idx] - cz;
  for (int j = 0; j < 64; ++j) {
    float4 w = *(const float4*)&W0f[j * 4];
    float v = fmaf(f2, w.z, fmaf(f1, w.y, fmaf(f0, w.x, bf0[j])));
    XT[j * 256 + t] = fmaxf(v, 0.0f);
  }
  __syncthreads();
  float acc[64];
#pragma unroll
  for (int j = 0; j < 64; ++j) acc[j] = bf1[j];
  for (int k = 0; k < 64; ++k) {
    float xk = XT[k * 256 + t];
    const float* wr = WT1 + k * 64;
#pragma unroll
    for (int j = 0; j < 64; ++j) acc[j] = fmaf(xk, wr[j], acc[j]);
  }
  __syncthreads();
#pragma unroll
  for (int j = 0; j < 64; ++j) XT[j * 256 + t] = fmaxf(acc[j], 0.0f);
  __syncthreads();
  float* outp = l1_pts + (size_t)q * 128;
  for (int jp = 0; jp < 2; ++jp) {
#pragma unroll
    for (int j = 0; j < 64; ++j) acc[j] = bf2[jp * 64 + j];
    for (int k = 0; k < 64; ++k) {
      float xk = XT[k * 256 + t];
      const float* wr = WT2 + k * 128 + jp * 64;
#pragma unroll
      for (int j = 0; j < 64; ++j) acc[j] = fmaf(xk, wr[j], acc[j]);
    }
#pragma unroll
    for (int j = 0; j < 64; ++j) {
      float m = fmaxf(acc[j], 0.0f);
      m = fmaxf(m, __shfl_xor(m, 1, 64));
      m = fmaxf(m, __shfl_xor(m, 2, 64));
      m = fmaxf(m, __shfl_xor(m, 4, 64));
      m = fmaxf(m, __shfl_xor(m, 8, 64));
      m = fmaxf(m, __shfl_xor(m, 16, 64));
      if (sm == 0) outp[jp * 64 + j] = m;
    }
  }
}

// ---------------- SA2 grouped MLP (131->128->128->256) + max over 64 samples ----------------
// SGPR weight path + chunk-2 k-loop: 2 weight rows (64 SGPRs) + 2 xk in flight
// per chunk so SMEM latency amortizes over 128 cyc of fma instead of 64.
// Accumulation order per acc[j] unchanged (k ascending).
#define F_STR 133
__global__ __launch_bounds__(256, 4) void sa2_mlp_kernel(
    const float* __restrict__ nx1, const float* __restrict__ l1_pts,
    const float* __restrict__ nx2, const int* __restrict__ gidx2,
    const float* __restrict__ WT1, const float* __restrict__ bf1,   // [132][128]
    const float* __restrict__ WT2, const float* __restrict__ bf2,   // [128][128]
    const float* __restrict__ WT3, const float* __restrict__ bf3,   // [128][256]
    float* __restrict__ l2_pts) {
  __shared__ float fb[64 * F_STR];
  int t = threadIdx.x;
  int lane = t & 63;
  int wg = __builtin_amdgcn_readfirstlane(t >> 6);
  int q = blockIdx.x;
  int b = q >> 7, s = q & 127;
  int idx = gidx2[(size_t)q * kNS2 + lane];
  const float* pr = l1_pts + ((size_t)(b * kS1) + idx) * 128;
  float* frow = fb + lane * F_STR;
#pragma unroll
  for (int i = 0; i < 8; ++i) {
    float4 v = *(const float4*)&pr[wg * 32 + i * 4];
    frow[3 + wg * 32 + i * 4 + 0] = v.x;
    frow[3 + wg * 32 + i * 4 + 1] = v.y;
    frow[3 + wg * 32 + i * 4 + 2] = v.z;
    frow[3 + wg * 32 + i * 4 + 3] = v.w;
  }
  if (wg == 0) {
    float cx = nx2[b * 384 + s];
    float cy = nx2[b * 384 + 128 + s];
    float cz = nx2[b * 384 + 256 + s];
    frow[0] = nx1[b * 1536 + idx] - cx;
    frow[1] = nx1[b * 1536 + 512 + idx] - cy;
    frow[2] = nx1[b * 1536 + 1024 + idx] - cz;
    frow[131] = 0.0f;
  }
  __syncthreads();
  float acc[32];
#pragma unroll
  for (int j = 0; j < 32; ++j) acc[j] = bf1[wg * 32 + j];
  for (int k = 0; k < 132; k += 2) {   // chunk-2: both rows + both xk issued first
    float x0 = frow[k];
    float x1 = frow[k + 1];
    const float* w0 = WT1 + k * 128 + wg * 32;
    const float* w1 = WT1 + (k + 1) * 128 + wg * 32;
#pragma unroll
    for (int j = 0; j < 32; ++j) acc[j] = fmaf(x0, w0[j], acc[j]);
#pragma unroll
    for (int j = 0; j < 32; ++j) acc[j] = fmaf(x1, w1[j], acc[j]);
  }
  __syncthreads();
#pragma unroll
  for (int j = 0; j < 32; ++j) frow[wg * 32 + j] = fmaxf(acc[j], 0.0f);
  __syncthreads();
#pragma unroll
  for (int j = 0; j < 32; ++j) acc[j] = bf2[wg * 32 + j];
  for (int k = 0; k < 128; k += 2) {
    float x0 = frow[k];
    float x1 = frow[k + 1];
    const float* w0 = WT2 + k * 128 + wg * 32;
    const float* w1 = WT2 + (k + 1) * 128 + wg * 32;
#pragma unroll
    for (int j = 0; j < 32; ++j) acc[j] = fmaf(x0, w0[j], acc[j]);
#pragma unroll
    for (int j = 0; j < 32; ++j) acc[j] = fmaf(x1, w1[j], acc[j]);
  }
  __syncthreads();
#pragma unroll
  for (int j = 0; j < 32; ++j) frow[wg * 32 + j] = fmaxf(acc[j], 0.0f);
  __syncthreads();
  float* outp = l2_pts + (size_t)q * 256;
  for (int jp = 0; jp < 2; ++jp) {
    int j0 = wg * 64 + jp * 32;
#pragma unroll
    for (int j = 0; j < 32; ++j) acc[j] = bf3[j0 + j];
    for (int k = 0; k < 128; k += 2) {
      float x0 = frow[k];
      float x1 = frow[k + 1];
      const float* w0 = WT3 + k * 256 + j0;
      const float* w1 = WT3 + (k + 1) * 256 + j0;
#pragma unroll
      for (int j = 0; j < 32; ++j) acc[j] = fmaf(x0, w0[j], acc[j]);
#pragma unroll
      for (int j = 0; j < 32; ++j) acc[j] = fmaf(x1, w1[j], acc[j]);
    }
#pragma unroll
    for (int j = 0; j < 32; ++j) {
      float m = fmaxf(acc[j], 0.0f);
      m = fmaxf(m, __shfl_xor(m, 1, 64));
      m = fmaxf(m, __shfl_xor(m, 2, 64));
      m = fmaxf(m, __shfl_xor(m, 4, 64));
      m = fmaxf(m, __shfl_xor(m, 8, 64));
      m = fmaxf(m, __shfl_xor(m, 16, 64));
      m = fmaxf(m, __shfl_xor(m, 32, 64));
      if (lane == 0) outp[j0 + j] = m;
    }
  }
}

// ---------------- SA3 (group-all): 259->256->512->1024 -> max over 128 ----------------
__global__ __launch_bounds__(256, 2) void sa3_passA_kernel(
    const float* __restrict__ nx2, const float* __restrict__ l2_pts,
    const float* __restrict__ WT, const float* __restrict__ bf,
    float* __restrict__ Y) {   // O = 256
  __shared__ float sF[16 * 260];
  int stile = blockIdx.x, t = threadIdx.x;
  int j = t;
  for (int i = t; i < 16 * 260; i += 256) {
    int row = stile * 16 + i / 260, k = i - (i / 260) * 260;
    int b = row >> 7, s = row & 127;
    float v;
    if (k < 3) v = nx2[b * 384 + k * 128 + s];
    else if (k < 259) v = l2_pts[(size_t)row * 256 + (k - 3)];
    else v = 0.0f;
    sF[i] = v;
  }
  __syncthreads();
  float acc[16];
  float bj = bf[j];
#pragma unroll
  for (int s = 0; s < 16; ++s) acc[s] = bj;
  for (int k = 0; k < 260; k += 4) {
    float w0 = WT[(size_t)k * 256 + j];
    float w1 = WT[(size_t)(k + 1) * 256 + j];
    float w2 = WT[(size_t)(k + 2) * 256 + j];
    float w3 = WT[(size_t)(k + 3) * 256 + j];
#pragma unroll
    for (int s = 0; s < 16; ++s) {
      const float4 fv = *(const float4*)&sF[s * 260 + k];
      acc[s] = fmaf(fv.x, w0, acc[s]);
      acc[s] = fmaf(fv.y, w1, acc[s]);
      acc[s] = fmaf(fv.z, w2, acc[s]);
      acc[s] = fmaf(fv.w, w3, acc[s]);
    }
  }
  float* yb = Y + (size_t)stile * 16 * 256 + j;
#pragma unroll
  for (int s = 0; s < 16; ++s) yb[(size_t)s * 256] = fmaxf(acc[s], 0.0f);
}

template <int KP>
__global__ __launch_bounds__(256, 2) void mlp_pass_kernel(
    const float* __restrict__ X, const float* __restrict__ WT, const float* __restrict__ bf,
    int O, float* __restrict__ Y) {
  __shared__ float sF[16 * KP];
  int stile = blockIdx.x, t = threadIdx.x;
  int j = blockIdx.y * 256 + t;
  const float* xb = X + (size_t)stile * 16 * KP;
  for (int i = t; i < 16 * KP; i += 256) sF[i] = xb[i];
  __syncthreads();
  float acc[16];
  float bj = bf[j];
#pragma unroll
  for (int s = 0; s < 16; ++s) acc[s] = bj;
  for (int k = 0; k < KP; k += 4) {
    float w0 = WT[(size_t)k * O + j];
    float w1 = WT[(size_t)(k + 1) * O + j];
    float w2 = WT[(size_t)(k + 2) * O + j];
    float w3 = WT[(size_t)(k + 3) * O + j];
#pragma unroll
    for (int s = 0; s < 16; ++s) {
      const float4 fv = *(const float4*)&sF[s * KP + k];
      acc[s] = fmaf(fv.x, w0, acc[s]);
      acc[s] = fmaf(fv.y, w1, acc[s]);
      acc[s] = fmaf(fv.z, w2, acc[s]);
      acc[s] = fmaf(fv.w, w3, acc[s]);
    }
  }
  float* yb = Y + (size_t)stile * 16 * O + j;
#pragma unroll
  for (int s = 0; s < 16; ++s) yb[(size_t)s * O] = fmaxf(acc[s], 0.0f);
}

__global__ __launch_bounds__(256, 2) void sa3_final_kernel(
    const float* __restrict__ X2g, const float* __restrict__ WTc, const float* __restrict__ bfc,
    float* __restrict__ out) {
  __shared__ float sF[16 * 512];
  int b = blockIdx.x, t = threadIdx.x;
  int j = blockIdx.y * 256 + t;
  float m = 0.0f;
  float bj = bfc[j];
  for (int st = 0; st < 8; ++st) {
    const float* xb = X2g + ((size_t)b * 128 + st * 16) * 512;
    for (int i = t; i < 16 * 512; i += 256) sF[i] = xb[i];
    __syncthreads();
    float acc[16];
#pragma unroll
    for (int s = 0; s < 16; ++s) acc[s] = bj;
    for (int k = 0; k < 512; k += 4) {
      float w0 = WTc[(size_t)k * 1024 + j];
      float w1 = WTc[(size_t)(k + 1) * 1024 + j];
      float w2 = WTc[(size_t)(k + 2) * 1024 + j];
      float w3 = WTc[(size_t)(k + 3) * 1024 + j];
#pragma unroll
      for (int s = 0; s < 16; ++s) {
        const float4 fv = *(const float4*)&sF[s * 512 + k];
        acc[s] = fmaf(fv.x, w0, acc[s]);
        acc[s] = fmaf(fv.y, w1, acc[s]);
        acc[s] = fmaf(fv.z, w2, acc[s]);
        acc[s] = fmaf(fv.w, w3, acc[s]);
      }
    }
#pragma unroll
    for (int s = 0; s < 16; ++s) m = fmaxf(m, fmaxf(acc[s], 0.0f));
    __syncthreads();
  }
  out[(size_t)b * 1024 + j] = m;
}

// ---------------- launch ----------------
extern "C" void kernel_launch(void* const* d_in, const int* in_sizes, int n_in,
                              void* d_out, int out_size, void* d_ws, size_t ws_size,
                              hipStream_t stream) {
  (void)in_sizes; (void)n_in; (void)out_size; (void)ws_size;
  const float* xyz = (const float*)d_in[0];
  auto WP = [&](int layer, int part) -> const float* {
    return (const float*)d_in[1 + layer * 4 + part];
  };
  float* wsf = (float*)d_ws;
  size_t cur = 0;
  auto alloc = [&](size_t n) { size_t o = cur; cur += (n + 63) & ~(size_t)63; return o; };
  size_t o_nx1 = alloc((size_t)kB * 3 * kS1);
  size_t o_nx2 = alloc((size_t)kB * 3 * kS2);
  size_t o_l1pts = alloc((size_t)kB * kS1 * 128);
  size_t o_l2pts = alloc((size_t)kB * kS2 * 256);
  size_t o_X1g = alloc((size_t)kB * kS2 * 256);
  size_t o_X2g = alloc((size_t)kB * kS2 * 512);
  size_t o_s1w0 = alloc(64 * 4), o_s1b0 = alloc(64);
  size_t o_s1w1 = alloc(64 * 64), o_s1b1 = alloc(64);
  size_t o_s1wt2 = alloc(64 * 128), o_s1b2 = alloc(128);
  size_t o_s2w1 = alloc(132 * 128), o_s2b1 = alloc(128);
  size_t o_s2wt2 = alloc(128 * 128), o_s2b2 = alloc(128);
  size_t o_s2w3 = alloc(128 * 256), o_s2b3 = alloc(256);
  size_t o_s3wtA = alloc(260 * 256), o_s3bA = alloc(256);
  size_t o_s3wtB = alloc(256 * 512), o_s3bB = alloc(512);
  size_t o_s3wtC = alloc(512 * 1024), o_s3bC = alloc(1024);
  size_t o_gidx1 = alloc((size_t)kB * kS1 * kNS1);
  size_t o_gidx2 = alloc((size_t)kB * kS2 * kNS2);
  int* gidx1 = (int*)(wsf + o_gidx1);
  int* gidx2 = (int*)(wsf + o_gidx2);

  // fused fold of all 9 layers
  FoldPack fp;
  const int OKKp[9][3] = {{64, 3, 4},     {64, 64, 64},   {128, 64, 64},
                          {128, 131, 132}, {128, 128, 128}, {256, 128, 128},
                          {256, 259, 260}, {512, 256, 256}, {1024, 512, 512}};
  float* wouts[9] = {wsf + o_s1w0, wsf + o_s1w1, wsf + o_s1wt2,
                     wsf + o_s2w1, wsf + o_s2wt2, wsf + o_s2w3,
                     wsf + o_s3wtA, wsf + o_s3wtB, wsf + o_s3wtC};
  float* bouts[9] = {wsf + o_s1b0, wsf + o_s1b1, wsf + o_s1b2,
                     wsf + o_s2b1, wsf + o_s2b2, wsf + o_s2b3,
                     wsf + o_s3bA, wsf + o_s3bB, wsf + o_s3bC};
  const int nblk[9] = {1, 4, 8, 17, 16, 32, 65, 128, 512};
  fp.cum[0] = 0;
  for (int L = 0; L < 9; ++L) {
    fp.d[L].W = WP(L, 0);
    fp.d[L].b = WP(L, 1);
    fp.d[L].g = WP(L, 2);
    fp.d[L].bt = WP(L, 3);
    fp.d[L].Wout = wouts[L];
    fp.d[L].bout = bouts[L];
    fp.d[L].O = OKKp[L][0];
    fp.d[L].K = OKKp[L][1];
    fp.d[L].Kp = OKKp[L][2];
    fp.d[L].transposed = (L == 0) ? 0 : 1;
    fp.cum[L + 1] = fp.cum[L] + nblk[L];
  }
  foldall_kernel<<<fp.cum[9], 256, 0, stream>>>(fp);

  // SA1
  fps16_kernel<kN1, kS1, 256><<<kB, 256, 0, stream>>>(xyz, wsf + o_nx1);
  bq_kernel<kN1, kS1, kNS1><<<(kB * kS1) / 4, 256, 0, stream>>>(xyz, wsf + o_nx1, 0.04f, gidx1);
  sa1_mlp_kernel<<<(kB * kS1) / 8, 256, 0, stream>>>(
      xyz, wsf + o_nx1, gidx1,
      wsf + o_s1w0, wsf + o_s1b0, wsf + o_s1w1, wsf + o_s1b1, wsf + o_s1wt2, wsf + o_s1b2,
      wsf + o_l1pts);

  // SA2
  fps4_kernel<kS1, kS2, 128><<<kB, 128, 0, stream>>>(wsf + o_nx1, wsf + o_nx2);
  bq_kernel<kS1, kS2, kNS2><<<(kB * kS2) / 4, 256, 0, stream>>>(wsf + o_nx1, wsf + o_nx2, 0.16f, gidx2);
  sa2_mlp_kernel<<<kB * kS2, 256, 0, stream>>>(
      wsf + o_nx1, wsf + o_l1pts, wsf + o_nx2, gidx2,
      wsf + o_s2w1, wsf + o_s2b1, wsf + o_s2wt2, wsf + o_s2b2, wsf + o_s2w3, wsf + o_s2b3,
      wsf + o_l2pts);

  // SA3 (group all)
  sa3_passA_kernel<<<256, 256, 0, stream>>>(wsf + o_nx2, wsf + o_l2pts,
                                            wsf + o_s3wtA, wsf + o_s3bA, wsf + o_X1g);
  mlp_pass_kernel<256><<<dim3(256, 2), 256, 0, stream>>>(wsf + o_X1g, wsf + o_s3wtB, wsf + o_s3bB, 512, wsf + o_X2g);
  sa3_final_kernel<<<dim3(kB, 4), 256, 0, stream>>>(wsf + o_X2g, wsf + o_s3wtC, wsf + o_s3bC, (float*)d_out);
}

// Round 11
// 1677.923 us; speedup vs baseline: 2.1960x; 1.0787x over previous
//
#include <hip/hip_runtime.h>
#include <hip/hip_bf16.h>
#include <cstddef>
#include <math.h>

#define kB 32
#define kN1 4096
#define kS1 512
#define kNS1 32
#define kS2 128
#define kNS2 64

// ---------------- fused weight folding for all 9 layers ----------------
struct FoldDesc {
  const float *W, *b, *g, *bt;
  float *Wout, *bout;
  int O, K, Kp, transposed;
};
struct FoldPack {
  FoldDesc d[9];
  int cum[10];
};

__global__ __launch_bounds__(256) void foldall_kernel(FoldPack p) {
  int blk = blockIdx.x;
  int L = 0;
#pragma unroll
  for (int i = 0; i < 9; ++i)
    if (blk >= p.cum[i + 1]) L = i + 1;
  FoldDesc d = p.d[L];
  int nb = p.cum[L + 1] - p.cum[L];
  int tid = (blk - p.cum[L]) * 256 + threadIdx.x;
  int stride = nb * 256;
  float inv = 1.0f / sqrtf(1.0f + 1e-5f);
  for (int i = tid; i < d.O * d.Kp; i += stride) {
    int o = i / d.Kp, k = i - o * d.Kp;
    float s = d.g[o] * inv;
    float w = (k < d.K) ? d.W[o * d.K + k] * s : 0.0f;
    if (d.transposed) d.Wout[k * d.O + o] = w;
    else d.Wout[o * d.Kp + k] = w;
  }
  for (int o = tid; o < d.O; o += stride) {
    d.bout[o] = d.b[o] * (d.g[o] * inv) + d.bt[o];
  }
}

// Canonical CDNA wave64 f32 max via DPP (VALU pipe only, no LDS/bpermute).
// Requires all inputs >= 0 (DPP 0-fill identity). Result valid in lane 63;
// returned broadcast via readlane.
__device__ __forceinline__ float wave_max_f32_nonneg(float x) {
#define DPP_MAXSTEP(CTRL)                                                     \
  {                                                                           \
    int o = __builtin_amdgcn_update_dpp(0, __float_as_int(x), (CTRL), 0xf, 0xf, true); \
    x = fmaxf(x, __int_as_float(o));                                          \
  }
  DPP_MAXSTEP(0x111)  // row_shr:1
  DPP_MAXSTEP(0x112)  // row_shr:2
  DPP_MAXSTEP(0x114)  // row_shr:4
  DPP_MAXSTEP(0x118)  // row_shr:8
  DPP_MAXSTEP(0x142)  // row_bcast:15
  DPP_MAXSTEP(0x143)  // row_bcast:31
#undef DPP_MAXSTEP
  return __int_as_float(__builtin_amdgcn_readlane(__float_as_int(x), 63));
}

// Publish predicate: unique max lane, or (rare tie) lane holding the minimum
// owned index among tied lanes -> exact "first max" semantics.
__device__ __forceinline__ bool fps_pub_lane(float bestf, float wmax, int besti) {
  unsigned long long m = __ballot(bestf == wmax);
  if (__popcll(m) == 1) return bestf == wmax;
  unsigned long long mm = m;
  int bidx = 0x7fffffff;
  while (mm) {
    int l = __ffsll(mm) - 1;
    int bi = __shfl(besti, l, 64);
    bidx = min(bidx, bi);
    mm &= mm - 1;
  }
  return (bestf == wmax) && (besti == bidx);
}

// ---------------- farthest point sampling ----------------
// Coords in LDS as float4 groups (12 ds_read_b128/thread/iter); dd state (16
// floats, named float4s) register-resident. One barrier/iter. DPP wave-max
// reduce (no bpermute). Cross-wave winner slots keep the exact u64 key
// {dist_bits<<32 | ~idx} -> exact first-max (lowest index) tie-break.
#define FPS_E(V, C, XV, YV, ZV, I)                                           \
  {                                                                          \
    float dx = __fsub_rn((XV), cx);                                          \
    float dy = __fsub_rn((YV), cy);                                          \
    float dz = __fsub_rn((ZV), cz);                                          \
    float d = fmaf(dz, dz, fmaf(dy, dy, __fmul_rn(dx, dx)));                 \
    float nd = fminf(dd##V.C, d);                                            \
    dd##V.C = nd;                                                            \
    if (nd > bestf) { bestf = nd; besti = (I); bx = (XV); by = (YV); bz = (ZV); } \
  }

#define FPS_GRP(V, R)                                                        \
  {                                                                          \
    float4 xg = sx4[t + (R) * T];                                            \
    float4 yg = sy4[t + (R) * T];                                            \
    float4 zg = sz4[t + (R) * T];                                            \
    int ibase = 4 * (t + (R) * T);                                           \
    FPS_E(V, x, xg.x, yg.x, zg.x, ibase)                                     \
    FPS_E(V, y, xg.y, yg.y, zg.y, ibase + 1)                                 \
    FPS_E(V, z, xg.z, yg.z, zg.z, ibase + 2)                                 \
    FPS_E(V, w, xg.w, yg.w, zg.w, ibase + 3)                                 \
  }

template <int N, int NP, int T>
__global__ __launch_bounds__(T, 1) void fps16_kernel(const float* __restrict__ xyz,
                                                     float* __restrict__ nx) {
  static_assert(N == 16 * T, "fps16: need exactly 16 points per thread");
  constexpr int W = T / 64;
  __shared__ float4 sx4[N / 4], sy4[N / 4], sz4[N / 4];
  __shared__ float4 sslot[2][W][2];
  __shared__ int fid[NP];
  int b = blockIdx.x, t = threadIdx.x;
  int w = t >> 6;
  const float* base = xyz + (size_t)b * 3 * N;
  float* sxf = (float*)sx4;
  float* syf = (float*)sy4;
  float* szf = (float*)sz4;
  for (int i = t; i < N; i += T) sxf[i] = base[i];
  for (int i = t; i < N; i += T) syf[i] = base[N + i];
  for (int i = t; i < N; i += T) szf[i] = base[2 * N + i];
  float4 dd0, dd1, dd2, dd3;
  dd0 = dd1 = dd2 = dd3 = make_float4(1e10f, 1e10f, 1e10f, 1e10f);
  if (t == 0) {
    fid[0] = 0;
    unsigned long long k0 = ~0ull;  // decodes to idx 0; max key so slot 0 wins iter 1
    sslot[0][0][0] = make_float4(__uint_as_float((unsigned)k0),
                                 __uint_as_float((unsigned)(k0 >> 32)),
                                 base[0], base[N]);
    sslot[0][0][1] = make_float4(base[2 * N], 0.0f, 0.0f, 0.0f);
  }
  if (t >= 64 && (t & 63) == 0) {
    sslot[0][w][0] = make_float4(0.0f, 0.0f, 0.0f, 0.0f);
    sslot[0][w][1] = make_float4(0.0f, 0.0f, 0.0f, 0.0f);
  }
  int par = 0;
  __syncthreads();
  for (int it = 1; it < NP; ++it) {
    float4 q0 = sslot[par][0][0];
    float4 q1 = sslot[par][0][1];
    unsigned long long mk =
        ((unsigned long long)__float_as_uint(q0.y) << 32) | __float_as_uint(q0.x);
    float cx = q0.z, cy = q0.w, cz = q1.x;
#pragma unroll
    for (int w2 = 1; w2 < W; ++w2) {
      float4 p0 = sslot[par][w2][0];
      float4 p1 = sslot[par][w2][1];
      unsigned long long k2 =
          ((unsigned long long)__float_as_uint(p0.y) << 32) | __float_as_uint(p0.x);
      if (k2 > mk) { mk = k2; cx = p0.z; cy = p0.w; cz = p1.x; }
    }
    if (t == 0) fid[it - 1] = (int)(~(unsigned)mk);
    float bestf = -1.0f;
    int besti = 4 * t;
    float bx = 0.0f, by = 0.0f, bz = 0.0f;
    FPS_GRP(0, 0)
    FPS_GRP(1, 1)
    FPS_GRP(2, 2)
    FPS_GRP(3, 3)
    // DPP wave-max (VALU pipe) + ballot publish; exact tie-break fallback
    float wmax = wave_max_f32_nonneg(bestf);
    if (fps_pub_lane(bestf, wmax, besti)) {
      unsigned long long key =
          ((unsigned long long)__float_as_uint(wmax) << 32) | (unsigned)(~besti);
      sslot[par ^ 1][w][0] = make_float4(__uint_as_float((unsigned)key),
                                         __uint_as_float((unsigned)(key >> 32)), bx, by);
      sslot[par ^ 1][w][1] = make_float4(bz, 0.0f, 0.0f, 0.0f);
    }
    __syncthreads();
    par ^= 1;
  }
  {
    float4 q0 = sslot[par][0][0];
    unsigned long long mk =
        ((unsigned long long)__float_as_uint(q0.y) << 32) | __float_as_uint(q0.x);
#pragma unroll
    for (int w2 = 1; w2 < W; ++w2) {
      float4 p0 = sslot[par][w2][0];
      unsigned long long k2 =
          ((unsigned long long)__float_as_uint(p0.y) << 32) | __float_as_uint(p0.x);
      if (k2 > mk) mk = k2;
    }
    if (t == 0) fid[NP - 1] = (int)(~(unsigned)mk);
  }
  __syncthreads();
  for (int s = t; s < NP; s += T) {
    int f = fid[s];
    nx[(size_t)b * 3 * NP + s] = sxf[f];
    nx[(size_t)b * 3 * NP + NP + s] = syf[f];
    nx[(size_t)b * 3 * NP + 2 * NP + s] = szf[f];
  }
}

// fps4: R=4 register-resident variant (fps2: N=512, T=128). Proven VGPR=20 shape.
#define FPS_STEP(V, C, IDXOFF)                                               \
  {                                                                          \
    float dx = __fsub_rn(px##V.C, cx);                                       \
    float dy = __fsub_rn(py##V.C, cy);                                       \
    float dz = __fsub_rn(pz##V.C, cz);                                       \
    float d = fmaf(dz, dz, fmaf(dy, dy, __fmul_rn(dx, dx)));                 \
    float nd = fminf(dd##V.C, d);                                            \
    dd##V.C = nd;                                                            \
    if (nd > bestf) {                                                        \
      bestf = nd; besti = t + (IDXOFF); bx = px##V.C; by = py##V.C; bz = pz##V.C; \
    }                                                                        \
  }

#define FPS_LD4(arr, src, off) \
  arr = make_float4((src)[(off)], (src)[(off) + T], (src)[(off) + 2 * T], (src)[(off) + 3 * T])

template <int N, int NP, int T>
__global__ __launch_bounds__(T, 1) void fps4_kernel(const float* __restrict__ xyz,
                                                    float* __restrict__ nx) {
  static_assert(N == 4 * T, "fps4: need exactly 4 points per thread");
  constexpr int W = T / 64;
  __shared__ float4 sslot[2][W][2];
  __shared__ int fid[NP];
  int b = blockIdx.x, t = threadIdx.x;
  int w = t >> 6;
  const float* base = xyz + (size_t)b * 3 * N;
  float4 px0, py0, pz0, dd0;
  FPS_LD4(px0, base, t);
  FPS_LD4(py0, base + N, t);
  FPS_LD4(pz0, base + 2 * N, t);
  dd0 = make_float4(1e10f, 1e10f, 1e10f, 1e10f);
  if (t == 0) {
    fid[0] = 0;
    unsigned long long k0 = ~0ull;
    sslot[0][0][0] = make_float4(__uint_as_float((unsigned)k0),
                                 __uint_as_float((unsigned)(k0 >> 32)), px0.x, py0.x);
    sslot[0][0][1] = make_float4(pz0.x, 0.0f, 0.0f, 0.0f);
  }
  if (t >= 64 && (t & 63) == 0) {
    sslot[0][w][0] = make_float4(0.0f, 0.0f, 0.0f, 0.0f);
    sslot[0][w][1] = make_float4(0.0f, 0.0f, 0.0f, 0.0f);
  }
  int par = 0;
  __syncthreads();
  for (int it = 1; it < NP; ++it) {
    float4 q0 = sslot[par][0][0];
    float4 q1 = sslot[par][0][1];
    unsigned long long mk =
        ((unsigned long long)__float_as_uint(q0.y) << 32) | __float_as_uint(q0.x);
    float cx = q0.z, cy = q0.w, cz = q1.x;
#pragma unroll
    for (int w2 = 1; w2 < W; ++w2) {
      float4 p0 = sslot[par][w2][0];
      float4 p1 = sslot[par][w2][1];
      unsigned long long k2 =
          ((unsigned long long)__float_as_uint(p0.y) << 32) | __float_as_uint(p0.x);
      if (k2 > mk) { mk = k2; cx = p0.z; cy = p0.w; cz = p1.x; }
    }
    if (t == 0) fid[it - 1] = (int)(~(unsigned)mk);
    float bestf = -1.0f;
    int besti = t;
    float bx = px0.x, by = py0.x, bz = pz0.x;
    FPS_STEP(0, x, 0) FPS_STEP(0, y, T) FPS_STEP(0, z, 2 * T) FPS_STEP(0, w, 3 * T)
    float wmax = wave_max_f32_nonneg(bestf);
    if (fps_pub_lane(bestf, wmax, besti)) {
      unsigned long long key =
          ((unsigned long long)__float_as_uint(wmax) << 32) | (unsigned)(~besti);
      sslot[par ^ 1][w][0] = make_float4(__uint_as_float((unsigned)key),
                                         __uint_as_float((unsigned)(key >> 32)), bx, by);
      sslot[par ^ 1][w][1] = make_float4(bz, 0.0f, 0.0f, 0.0f);
    }
    __syncthreads();
    par ^= 1;
  }
  {
    float4 q0 = sslot[par][0][0];
    unsigned long long mk =
        ((unsigned long long)__float_as_uint(q0.y) << 32) | __float_as_uint(q0.x);
#pragma unroll
    for (int w2 = 1; w2 < W; ++w2) {
      float4 p0 = sslot[par][w2][0];
      unsigned long long k2 =
          ((unsigned long long)__float_as_uint(p0.y) << 32) | __float_as_uint(p0.x);
      if (k2 > mk) mk = k2;
    }
    if (t == 0) fid[NP - 1] = (int)(~(unsigned)mk);
  }
  __syncthreads();
  for (int s = t; s < NP; s += T) {
    int f = fid[s];
    nx[(size_t)b * 3 * NP + s] = base[f];
    nx[(size_t)b * 3 * NP + NP + s] = base[N + f];
    nx[(size_t)b * 3 * NP + 2 * NP + s] = base[2 * N + f];
  }
}

// ---------------- ball query ----------------
template <int NPTS, int NQ, int NS>
__global__ void bq_kernel(const float* __restrict__ pts, const float* __restrict__ qry,
                          float r2, int* __restrict__ gidx) {
  int gw = (blockIdx.x * blockDim.x + threadIdx.x) >> 6;
  int lane = threadIdx.x & 63;
  if (gw >= kB * NQ) return;
  int b = gw / NQ, s = gw - b * NQ;
  const float* pb = pts + (size_t)b * 3 * NPTS;
  float cx = qry[(size_t)b * 3 * NQ + s];
  float cy = qry[(size_t)b * 3 * NQ + NQ + s];
  float cz = qry[(size_t)b * 3 * NQ + 2 * NQ + s];
  float ss = fmaf(cz, cz, fmaf(cy, cy, __fmul_rn(cx, cx)));
  int* out = gidx + (size_t)gw * NS;
  int have = 0, first = 0;
  bool gotfirst = false;
  for (int n0 = 0; n0 < NPTS; n0 += 64) {
    int n = n0 + lane;
    float x = pb[n], y = pb[NPTS + n], z = pb[2 * NPTS + n];
    float dd = fmaf(z, z, fmaf(y, y, __fmul_rn(x, x)));
    float cross = fmaf(cz, z, fmaf(cy, y, __fmul_rn(cx, x)));
    float sqr = __fsub_rn(__fadd_rn(ss, dd), __fmul_rn(2.0f, cross));
    bool pred = !(sqr > r2);
    unsigned long long mask = __ballot(pred);
    if (!gotfirst && mask) { first = n0 + (__ffsll(mask) - 1); gotfirst = true; }
    if (pred) {
      int pos = have + __popcll(mask & ((1ull << lane) - 1ull));
      if (pos < NS) out[pos] = n;
    }
    have += __popcll(mask);
    if (have >= NS) break;
  }
  for (int slot = have + lane; slot < NS; slot += 64) out[slot] = first;
}

// ---------------- SA1 grouped MLP (3->64->64->128) + max over 32 samples ----------------
// SGPR weight path: wr pointers are block-uniform -> s_load; weights feed fmas
// as SGPR operands (free). LDS 64KB -> 2 blocks/CU.
__global__ __launch_bounds__(256, 2) void sa1_mlp_kernel(
    const float* __restrict__ xyz, const float* __restrict__ nx1,
    const int* __restrict__ gidx,
    const float* __restrict__ W0f, const float* __restrict__ bf0,   // [64][4], [64]
    const float* __restrict__ WT1, const float* __restrict__ bf1,   // [64][64]
    const float* __restrict__ WT2, const float* __restrict__ bf2,   // [64][128]
    float* __restrict__ l1_pts) {
  __shared__ float XT[64 * 256];   // reused for X1 then X2
  int t = threadIdx.x;
  int qi = t >> 5, sm = t & 31;
  int q = blockIdx.x * 8 + qi;
  int b = q >> 9, s = q & 511;
  int idx = gidx[(size_t)q * kNS1 + sm];
  float cx = nx1[b * 1536 + s];
  float cy = nx1[b * 1536 + 512 + s];
  float cz = nx1[b * 1536 + 1024 + s];
  const float* pb = xyz + (size_t)b * 3 * kN1;
  float f0 = pb[idx] - cx, f1 = pb[kN1 + idx] - cy, f2 = pb[2 * kN1 + idx] - cz;
  for (int j = 0; j < 64; ++j) {
    float4 w = *(const float4*)&W0f[j * 4];
    float v = fmaf(f2, w.z, fmaf(f1, w.y, fmaf(f0, w.x, bf0[j])));
    XT[j * 256 + t] = fmaxf(v, 0.0f);
  }
  __syncthreads();
  float acc[64];
#pragma unroll
  for (int j = 0; j < 64; ++j) acc[j] = bf1[j];
  for (int k = 0; k < 64; ++k) {
    float xk = XT[k * 256 + t];
    const float* wr = WT1 + k * 64;
#pragma unroll
    for (int j = 0; j < 64; ++j) acc[j] = fmaf(xk, wr[j], acc[j]);
  }
  __syncthreads();
#pragma unroll
  for (int j = 0; j < 64; ++j) XT[j * 256 + t] = fmaxf(acc[j], 0.0f);
  __syncthreads();
  float* outp = l1_pts + (size_t)q * 128;
  for (int jp = 0; jp < 2; ++jp) {
#pragma unroll
    for (int j = 0; j < 64; ++j) acc[j] = bf2[jp * 64 + j];
    for (int k = 0; k < 64; ++k) {
      float xk = XT[k * 256 + t];
      const float* wr = WT2 + k * 128 + jp * 64;
#pragma unroll
      for (int j = 0; j < 64; ++j) acc[j] = fmaf(xk, wr[j], acc[j]);
    }
#pragma unroll
    for (int j = 0; j < 64; ++j) {
      float m = fmaxf(acc[j], 0.0f);
      m = fmaxf(m, __shfl_xor(m, 1, 64));
      m = fmaxf(m, __shfl_xor(m, 2, 64));
      m = fmaxf(m, __shfl_xor(m, 4, 64));
      m = fmaxf(m, __shfl_xor(m, 8, 64));
      m = fmaxf(m, __shfl_xor(m, 16, 64));
      if (sm == 0) outp[jp * 64 + j] = m;
    }
  }
}

// ---------------- SA2 grouped MLP (131->128->128->256) + max over 64 samples ----------------
// SGPR weight path + chunk-2 k-loop: 2 weight rows (64 SGPRs) + 2 xk in flight
// per chunk so SMEM latency amortizes over 128 cyc of fma instead of 64.
#define F_STR 133
__global__ __launch_bounds__(256, 4) void sa2_mlp_kernel(
    const float* __restrict__ nx1, const float* __restrict__ l1_pts,
    const float* __restrict__ nx2, const int* __restrict__ gidx2,
    const float* __restrict__ WT1, const float* __restrict__ bf1,   // [132][128]
    const float* __restrict__ WT2, const float* __restrict__ bf2,   // [128][128]
    const float* __restrict__ WT3, const float* __restrict__ bf3,   // [128][256]
    float* __restrict__ l2_pts) {
  __shared__ float fb[64 * F_STR];
  int t = threadIdx.x;
  int lane = t & 63;
  int wg = __builtin_amdgcn_readfirstlane(t >> 6);
  int q = blockIdx.x;
  int b = q >> 7, s = q & 127;
  int idx = gidx2[(size_t)q * kNS2 + lane];
  const float* pr = l1_pts + ((size_t)(b * kS1) + idx) * 128;
  float* frow = fb + lane * F_STR;
#pragma unroll
  for (int i = 0; i < 8; ++i) {
    float4 v = *(const float4*)&pr[wg * 32 + i * 4];
    frow[3 + wg * 32 + i * 4 + 0] = v.x;
    frow[3 + wg * 32 + i * 4 + 1] = v.y;
    frow[3 + wg * 32 + i * 4 + 2] = v.z;
    frow[3 + wg * 32 + i * 4 + 3] = v.w;
  }
  if (wg == 0) {
    float cx = nx2[b * 384 + s];
    float cy = nx2[b * 384 + 128 + s];
    float cz = nx2[b * 384 + 256 + s];
    frow[0] = nx1[b * 1536 + idx] - cx;
    frow[1] = nx1[b * 1536 + 512 + idx] - cy;
    frow[2] = nx1[b * 1536 + 1024 + idx] - cz;
    frow[131] = 0.0f;
  }
  __syncthreads();
  float acc[32];
#pragma unroll
  for (int j = 0; j < 32; ++j) acc[j] = bf1[wg * 32 + j];
  for (int k = 0; k < 132; k += 2) {   // chunk-2: both rows + both xk issued first
    float x0 = frow[k];
    float x1 = frow[k + 1];
    const float* w0 = WT1 + k * 128 + wg * 32;
    const float* w1 = WT1 + (k + 1) * 128 + wg * 32;
#pragma unroll
    for (int j = 0; j < 32; ++j) acc[j] = fmaf(x0, w0[j], acc[j]);
#pragma unroll
    for (int j = 0; j < 32; ++j) acc[j] = fmaf(x1, w1[j], acc[j]);
  }
  __syncthreads();
#pragma unroll
  for (int j = 0; j < 32; ++j) frow[wg * 32 + j] = fmaxf(acc[j], 0.0f);
  __syncthreads();
#pragma unroll
  for (int j = 0; j < 32; ++j) acc[j] = bf2[wg * 32 + j];
  for (int k = 0; k < 128; k += 2) {
    float x0 = frow[k];
    float x1 = frow[k + 1];
    const float* w0 = WT2 + k * 128 + wg * 32;
    const float* w1 = WT2 + (k + 1) * 128 + wg * 32;
#pragma unroll
    for (int j = 0; j < 32; ++j) acc[j] = fmaf(x0, w0[j], acc[j]);
#pragma unroll
    for (int j = 0; j < 32; ++j) acc[j] = fmaf(x1, w1[j], acc[j]);
  }
  __syncthreads();
#pragma unroll
  for (int j = 0; j < 32; ++j) frow[wg * 32 + j] = fmaxf(acc[j], 0.0f);
  __syncthreads();
  float* outp = l2_pts + (size_t)q * 256;
  for (int jp = 0; jp < 2; ++jp) {
    int j0 = wg * 64 + jp * 32;
#pragma unroll
    for (int j = 0; j < 32; ++j) acc[j] = bf3[j0 + j];
    for (int k = 0; k < 128; k += 2) {
      float x0 = frow[k];
      float x1 = frow[k + 1];
      const float* w0 = WT3 + k * 256 + j0;
      const float* w1 = WT3 + (k + 1) * 256 + j0;
#pragma unroll
      for (int j = 0; j < 32; ++j) acc[j] = fmaf(x0, w0[j], acc[j]);
#pragma unroll
      for (int j = 0; j < 32; ++j) acc[j] = fmaf(x1, w1[j], acc[j]);
    }
#pragma unroll
    for (int j = 0; j < 32; ++j) {
      float m = fmaxf(acc[j], 0.0f);
      m = fmaxf(m, __shfl_xor(m, 1, 64));
      m = fmaxf(m, __shfl_xor(m, 2, 64));
      m = fmaxf(m, __shfl_xor(m, 4, 64));
      m = fmaxf(m, __shfl_xor(m, 8, 64));
      m = fmaxf(m, __shfl_xor(m, 16, 64));
      m = fmaxf(m, __shfl_xor(m, 32, 64));
      if (lane == 0) outp[j0 + j] = m;
    }
  }
}

// ---------------- SA3 (group-all): 259->256->512->1024 -> max over 128 ----------------
__global__ __launch_bounds__(256, 2) void sa3_passA_kernel(
    const float* __restrict__ nx2, const float* __restrict__ l2_pts,
    const float* __restrict__ WT, const float* __restrict__ bf,
    float* __restrict__ Y) {   // O = 256
  __shared__ float sF[16 * 260];
  int stile = blockIdx.x, t = threadIdx.x;
  int j = t;
  for (int i = t; i < 16 * 260; i += 256) {
    int row = stile * 16 + i / 260, k = i - (i / 260) * 260;
    int b = row >> 7, s = row & 127;
    float v;
    if (k < 3) v = nx2[b * 384 + k * 128 + s];
    else if (k < 259) v = l2_pts[(size_t)row * 256 + (k - 3)];
    else v = 0.0f;
    sF[i] = v;
  }
  __syncthreads();
  float acc[16];
  float bj = bf[j];
#pragma unroll
  for (int s = 0; s < 16; ++s) acc[s] = bj;
  for (int k = 0; k < 260; k += 4) {
    float w0 = WT[(size_t)k * 256 + j];
    float w1 = WT[(size_t)(k + 1) * 256 + j];
    float w2 = WT[(size_t)(k + 2) * 256 + j];
    float w3 = WT[(size_t)(k + 3) * 256 + j];
#pragma unroll
    for (int s = 0; s < 16; ++s) {
      const float4 fv = *(const float4*)&sF[s * 260 + k];
      acc[s] = fmaf(fv.x, w0, acc[s]);
      acc[s] = fmaf(fv.y, w1, acc[s]);
      acc[s] = fmaf(fv.z, w2, acc[s]);
      acc[s] = fmaf(fv.w, w3, acc[s]);
    }
  }
  float* yb = Y + (size_t)stile * 16 * 256 + j;
#pragma unroll
  for (int s = 0; s < 16; ++s) yb[(size_t)s * 256] = fmaxf(acc[s], 0.0f);
}

template <int KP>
__global__ __launch_bounds__(256, 2) void mlp_pass_kernel(
    const float* __restrict__ X, const float* __restrict__ WT, const float* __restrict__ bf,
    int O, float* __restrict__ Y) {
  __shared__ float sF[16 * KP];
  int stile = blockIdx.x, t = threadIdx.x;
  int j = blockIdx.y * 256 + t;
  const float* xb = X + (size_t)stile * 16 * KP;
  for (int i = t; i < 16 * KP; i += 256) sF[i] = xb[i];
  __syncthreads();
  float acc[16];
  float bj = bf[j];
#pragma unroll
  for (int s = 0; s < 16; ++s) acc[s] = bj;
  for (int k = 0; k < KP; k += 4) {
    float w0 = WT[(size_t)k * O + j];
    float w1 = WT[(size_t)(k + 1) * O + j];
    float w2 = WT[(size_t)(k + 2) * O + j];
    float w3 = WT[(size_t)(k + 3) * O + j];
#pragma unroll
    for (int s = 0; s < 16; ++s) {
      const float4 fv = *(const float4*)&sF[s * KP + k];
      acc[s] = fmaf(fv.x, w0, acc[s]);
      acc[s] = fmaf(fv.y, w1, acc[s]);
      acc[s] = fmaf(fv.z, w2, acc[s]);
      acc[s] = fmaf(fv.w, w3, acc[s]);
    }
  }
  float* yb = Y + (size_t)stile * 16 * O + j;
#pragma unroll
  for (int s = 0; s < 16; ++s) yb[(size_t)s * O] = fmaxf(acc[s], 0.0f);
}

__global__ __launch_bounds__(256, 2) void sa3_final_kernel(
    const float* __restrict__ X2g, const float* __restrict__ WTc, const float* __restrict__ bfc,
    float* __restrict__ out) {
  __shared__ float sF[16 * 512];
  int b = blockIdx.x, t = threadIdx.x;
  int j = blockIdx.y * 256 + t;
  float m = 0.0f;
  float bj = bfc[j];
  for (int st = 0; st < 8; ++st) {
    const float* xb = X2g + ((size_t)b * 128 + st * 16) * 512;
    for (int i = t; i < 16 * 512; i += 256) sF[i] = xb[i];
    __syncthreads();
    float acc[16];
#pragma unroll
    for (int s = 0; s < 16; ++s) acc[s] = bj;
    for (int k = 0; k < 512; k += 4) {
      float w0 = WTc[(size_t)k * 1024 + j];
      float w1 = WTc[(size_t)(k + 1) * 1024 + j];
      float w2 = WTc[(size_t)(k + 2) * 1024 + j];
      float w3 = WTc[(size_t)(k + 3) * 1024 + j];
#pragma unroll
      for (int s = 0; s < 16; ++s) {
        const float4 fv = *(const float4*)&sF[s * 512 + k];
        acc[s] = fmaf(fv.x, w0, acc[s]);
        acc[s] = fmaf(fv.y, w1, acc[s]);
        acc[s] = fmaf(fv.z, w2, acc[s]);
        acc[s] = fmaf(fv.w, w3, acc[s]);
      }
    }
#pragma unroll
    for (int s = 0; s < 16; ++s) m = fmaxf(m, fmaxf(acc[s], 0.0f));
    __syncthreads();
  }
  out[(size_t)b * 1024 + j] = m;
}

// ---------------- launch ----------------
extern "C" void kernel_launch(void* const* d_in, const int* in_sizes, int n_in,
                              void* d_out, int out_size, void* d_ws, size_t ws_size,
                              hipStream_t stream) {
  (void)in_sizes; (void)n_in; (void)out_size; (void)ws_size;
  const float* xyz = (const float*)d_in[0];
  auto WP = [&](int layer, int part) -> const float* {
    return (const float*)d_in[1 + layer * 4 + part];
  };
  float* wsf = (float*)d_ws;
  size_t cur = 0;
  auto alloc = [&](size_t n) { size_t o = cur; cur += (n + 63) & ~(size_t)63; return o; };
  size_t o_nx1 = alloc((size_t)kB * 3 * kS1);
  size_t o_nx2 = alloc((size_t)kB * 3 * kS2);
  size_t o_l1pts = alloc((size_t)kB * kS1 * 128);
  size_t o_l2pts = alloc((size_t)kB * kS2 * 256);
  size_t o_X1g = alloc((size_t)kB * kS2 * 256);
  size_t o_X2g = alloc((size_t)kB * kS2 * 512);
  size_t o_s1w0 = alloc(64 * 4), o_s1b0 = alloc(64);
  size_t o_s1w1 = alloc(64 * 64), o_s1b1 = alloc(64);
  size_t o_s1wt2 = alloc(64 * 128), o_s1b2 = alloc(128);
  size_t o_s2w1 = alloc(132 * 128), o_s2b1 = alloc(128);
  size_t o_s2wt2 = alloc(128 * 128), o_s2b2 = alloc(128);
  size_t o_s2w3 = alloc(128 * 256), o_s2b3 = alloc(256);
  size_t o_s3wtA = alloc(260 * 256), o_s3bA = alloc(256);
  size_t o_s3wtB = alloc(256 * 512), o_s3bB = alloc(512);
  size_t o_s3wtC = alloc(512 * 1024), o_s3bC = alloc(1024);
  size_t o_gidx1 = alloc((size_t)kB * kS1 * kNS1);
  size_t o_gidx2 = alloc((size_t)kB * kS2 * kNS2);
  int* gidx1 = (int*)(wsf + o_gidx1);
  int* gidx2 = (int*)(wsf + o_gidx2);

  // fused fold of all 9 layers
  FoldPack fp;
  const int OKKp[9][3] = {{64, 3, 4},     {64, 64, 64},   {128, 64, 64},
                          {128, 131, 132}, {128, 128, 128}, {256, 128, 128},
                          {256, 259, 260}, {512, 256, 256}, {1024, 512, 512}};
  float* wouts[9] = {wsf + o_s1w0, wsf + o_s1w1, wsf + o_s1wt2,
                     wsf + o_s2w1, wsf + o_s2wt2, wsf + o_s2w3,
                     wsf + o_s3wtA, wsf + o_s3wtB, wsf + o_s3wtC};
  float* bouts[9] = {wsf + o_s1b0, wsf + o_s1b1, wsf + o_s1b2,
                     wsf + o_s2b1, wsf + o_s2b2, wsf + o_s2b3,
                     wsf + o_s3bA, wsf + o_s3bB, wsf + o_s3bC};
  const int nblk[9] = {1, 4, 8, 17, 16, 32, 65, 128, 512};
  fp.cum[0] = 0;
  for (int L = 0; L < 9; ++L) {
    fp.d[L].W = WP(L, 0);
    fp.d[L].b = WP(L, 1);
    fp.d[L].g = WP(L, 2);
    fp.d[L].bt = WP(L, 3);
    fp.d[L].Wout = wouts[L];
    fp.d[L].bout = bouts[L];
    fp.d[L].O = OKKp[L][0];
    fp.d[L].K = OKKp[L][1];
    fp.d[L].Kp = OKKp[L][2];
    fp.d[L].transposed = (L == 0) ? 0 : 1;
    fp.cum[L + 1] = fp.cum[L] + nblk[L];
  }
  foldall_kernel<<<fp.cum[9], 256, 0, stream>>>(fp);

  // SA1
  fps16_kernel<kN1, kS1, 256><<<kB, 256, 0, stream>>>(xyz, wsf + o_nx1);
  bq_kernel<kN1, kS1, kNS1><<<(kB * kS1) / 4, 256, 0, stream>>>(xyz, wsf + o_nx1, 0.04f, gidx1);
  sa1_mlp_kernel<<<(kB * kS1) / 8, 256, 0, stream>>>(
      xyz, wsf + o_nx1, gidx1,
      wsf + o_s1w0, wsf + o_s1b0, wsf + o_s1w1, wsf + o_s1b1, wsf + o_s1wt2, wsf + o_s1b2,
      wsf + o_l1pts);

  // SA2
  fps4_kernel<kS1, kS2, 128><<<kB, 128, 0, stream>>>(wsf + o_nx1, wsf + o_nx2);
  bq_kernel<kS1, kS2, kNS2><<<(kB * kS2) / 4, 256, 0, stream>>>(wsf + o_nx1, wsf + o_nx2, 0.16f, gidx2);
  sa2_mlp_kernel<<<kB * kS2, 256, 0, stream>>>(
      wsf + o_nx1, wsf + o_l1pts, wsf + o_nx2, gidx2,
      wsf + o_s2w1, wsf + o_s2b1, wsf + o_s2wt2, wsf + o_s2b2, wsf + o_s2w3, wsf + o_s2b3,
      wsf + o_l2pts);

  // SA3 (group all)
  sa3_passA_kernel<<<256, 256, 0, stream>>>(wsf + o_nx2, wsf + o_l2pts,
                                            wsf + o_s3wtA, wsf + o_s3bA, wsf + o_X1g);
  mlp_pass_kernel<256><<<dim3(256, 2), 256, 0, stream>>>(wsf + o_X1g, wsf + o_s3wtB, wsf + o_s3bB, 512, wsf + o_X2g);
  sa3_final_kernel<<<dim3(kB, 4), 256, 0, stream>>>(wsf + o_X2g, wsf + o_s3wtC, wsf + o_s3bC, (float*)d_out);
}

// Round 12
// 1506.334 us; speedup vs baseline: 2.4461x; 1.1139x over previous
//
#include <hip/hip_runtime.h>
#include <hip/hip_bf16.h>
#include <cstddef>
#include <math.h>

#define kB 32
#define kN1 4096
#define kS1 512
#define kNS1 32
#define kS2 128
#define kNS2 64

// ---------------- fused weight folding for all 9 layers ----------------
struct FoldDesc {
  const float *W, *b, *g, *bt;
  float *Wout, *bout;
  int O, K, Kp, transposed;
};
struct FoldPack {
  FoldDesc d[9];
  int cum[10];
};

__global__ __launch_bounds__(256) void foldall_kernel(FoldPack p) {
  int blk = blockIdx.x;
  int L = 0;
#pragma unroll
  for (int i = 0; i < 9; ++i)
    if (blk >= p.cum[i + 1]) L = i + 1;
  FoldDesc d = p.d[L];
  int nb = p.cum[L + 1] - p.cum[L];
  int tid = (blk - p.cum[L]) * 256 + threadIdx.x;
  int stride = nb * 256;
  float inv = 1.0f / sqrtf(1.0f + 1e-5f);
  for (int i = tid; i < d.O * d.Kp; i += stride) {
    int o = i / d.Kp, k = i - o * d.Kp;
    float s = d.g[o] * inv;
    float w = (k < d.K) ? d.W[o * d.K + k] * s : 0.0f;
    if (d.transposed) d.Wout[k * d.O + o] = w;
    else d.Wout[o * d.Kp + k] = w;
  }
  for (int o = tid; o < d.O; o += stride) {
    d.bout[o] = d.b[o] * (d.g[o] * inv) + d.bt[o];
  }
}

// Canonical CDNA wave64 f32 max via DPP (VALU pipe only, no LDS/bpermute).
// Requires all inputs >= 0 (DPP 0-fill identity). Result broadcast via readlane.
__device__ __forceinline__ float wave_max_f32_nonneg(float x) {
#define DPP_MAXSTEP(CTRL)                                                     \
  {                                                                           \
    int o = __builtin_amdgcn_update_dpp(0, __float_as_int(x), (CTRL), 0xf, 0xf, true); \
    x = fmaxf(x, __int_as_float(o));                                          \
  }
  DPP_MAXSTEP(0x111)  // row_shr:1
  DPP_MAXSTEP(0x112)  // row_shr:2
  DPP_MAXSTEP(0x114)  // row_shr:4
  DPP_MAXSTEP(0x118)  // row_shr:8
  DPP_MAXSTEP(0x142)  // row_bcast:15
  DPP_MAXSTEP(0x143)  // row_bcast:31
#undef DPP_MAXSTEP
  return __int_as_float(__builtin_amdgcn_readlane(__float_as_int(x), 63));
}

// Publish predicate: unique max lane, or (rare tie) lane holding the minimum
// owned index among tied lanes -> exact "first max" semantics.
__device__ __forceinline__ bool fps_pub_lane(float bestf, float wmax, int besti) {
  unsigned long long m = __ballot(bestf == wmax);
  if (__popcll(m) == 1) return bestf == wmax;
  unsigned long long mm = m;
  int bidx = 0x7fffffff;
  while (mm) {
    int l = __ffsll(mm) - 1;
    int bi = __shfl(besti, l, 64);
    bidx = min(bidx, bi);
    mm &= mm - 1;
  }
  return (bestf == wmax) && (besti == bidx);
}

// ---------------- farthest point sampling ----------------
// Coords in LDS as float4 groups (12 ds_read_b128/thread/iter); dd state (16
// floats, named float4s) register-resident. One barrier/iter. DPP wave-max.
// Winner slots hold ONLY the u64 key {dist_bits<<32 | ~idx} (b64 scan);
// centroid coords fetched by index via 3 broadcast ds_read_b32 -> no per-point
// coord tracking (3 fewer cndmask/point), publish is a single ds_write_b64.
#define FPS_E(V, C, XV, YV, ZV, I)                                           \
  {                                                                          \
    float dx = __fsub_rn((XV), cx);                                          \
    float dy = __fsub_rn((YV), cy);                                          \
    float dz = __fsub_rn((ZV), cz);                                          \
    float d = fmaf(dz, dz, fmaf(dy, dy, __fmul_rn(dx, dx)));                 \
    float nd = fminf(dd##V.C, d);                                            \
    dd##V.C = nd;                                                            \
    if (nd > bestf) { bestf = nd; besti = (I); }                             \
  }

#define FPS_GRP(V, R)                                                        \
  {                                                                          \
    float4 xg = sx4[t + (R) * T];                                            \
    float4 yg = sy4[t + (R) * T];                                            \
    float4 zg = sz4[t + (R) * T];                                            \
    int ibase = 4 * (t + (R) * T);                                           \
    FPS_E(V, x, xg.x, yg.x, zg.x, ibase)                                     \
    FPS_E(V, y, xg.y, yg.y, zg.y, ibase + 1)                                 \
    FPS_E(V, z, xg.z, yg.z, zg.z, ibase + 2)                                 \
    FPS_E(V, w, xg.w, yg.w, zg.w, ibase + 3)                                 \
  }

template <int N, int NP, int T>
__global__ __launch_bounds__(T, 1) void fps16_kernel(const float* __restrict__ xyz,
                                                     float* __restrict__ nx) {
  static_assert(N == 16 * T, "fps16: need exactly 16 points per thread");
  constexpr int W = T / 64;
  __shared__ float4 sx4[N / 4], sy4[N / 4], sz4[N / 4];
  __shared__ unsigned long long skey[2][W];
  __shared__ int fid[NP];
  int b = blockIdx.x, t = threadIdx.x;
  int w = t >> 6;
  const float* base = xyz + (size_t)b * 3 * N;
  float* sxf = (float*)sx4;
  float* syf = (float*)sy4;
  float* szf = (float*)sz4;
  for (int i = t; i < N; i += T) sxf[i] = base[i];
  for (int i = t; i < N; i += T) syf[i] = base[N + i];
  for (int i = t; i < N; i += T) szf[i] = base[2 * N + i];
  float4 dd0, dd1, dd2, dd3;
  dd0 = dd1 = dd2 = dd3 = make_float4(1e10f, 1e10f, 1e10f, 1e10f);
  if (t < W) skey[0][t] = (t == 0) ? ~0ull : 0ull;  // ~0ull decodes to idx 0
  if (t == 0) fid[0] = 0;
  int par = 0;
  __syncthreads();
  for (int it = 1; it < NP; ++it) {
    // scan W key slots (b64 broadcast reads)
    unsigned long long mk = skey[par][0];
#pragma unroll
    for (int w2 = 1; w2 < W; ++w2) {
      unsigned long long k2 = skey[par][w2];
      if (k2 > mk) mk = k2;
    }
    int wi = (int)(~(unsigned)mk);
    if (t == 0) fid[it - 1] = wi;
    // centroid coords by index (broadcast b32 reads)
    float cx = sxf[wi], cy = syf[wi], cz = szf[wi];
    float bestf = -1.0f;
    int besti = 4 * t;
    FPS_GRP(0, 0)
    FPS_GRP(1, 1)
    FPS_GRP(2, 2)
    FPS_GRP(3, 3)
    // DPP wave-max (VALU pipe) + ballot publish; exact tie-break fallback
    float wmax = wave_max_f32_nonneg(bestf);
    if (fps_pub_lane(bestf, wmax, besti)) {
      skey[par ^ 1][w] =
          ((unsigned long long)__float_as_uint(wmax) << 32) | (unsigned)(~besti);
    }
    __syncthreads();
    par ^= 1;
  }
  {
    unsigned long long mk = skey[par][0];
#pragma unroll
    for (int w2 = 1; w2 < W; ++w2) {
      unsigned long long k2 = skey[par][w2];
      if (k2 > mk) mk = k2;
    }
    if (t == 0) fid[NP - 1] = (int)(~(unsigned)mk);
  }
  __syncthreads();
  for (int s = t; s < NP; s += T) {
    int f = fid[s];
    nx[(size_t)b * 3 * NP + s] = sxf[f];
    nx[(size_t)b * 3 * NP + NP + s] = syf[f];
    nx[(size_t)b * 3 * NP + 2 * NP + s] = szf[f];
  }
}

// fps4: R=4 register-resident variant (fps2: N=512, T=128). Proven VGPR=20 shape.
#define FPS_STEP(V, C, IDXOFF)                                               \
  {                                                                          \
    float dx = __fsub_rn(px##V.C, cx);                                       \
    float dy = __fsub_rn(py##V.C, cy);                                       \
    float dz = __fsub_rn(pz##V.C, cz);                                       \
    float d = fmaf(dz, dz, fmaf(dy, dy, __fmul_rn(dx, dx)));                 \
    float nd = fminf(dd##V.C, d);                                            \
    dd##V.C = nd;                                                            \
    if (nd > bestf) {                                                        \
      bestf = nd; besti = t + (IDXOFF); bx = px##V.C; by = py##V.C; bz = pz##V.C; \
    }                                                                        \
  }

#define FPS_LD4(arr, src, off) \
  arr = make_float4((src)[(off)], (src)[(off) + T], (src)[(off) + 2 * T], (src)[(off) + 3 * T])

template <int N, int NP, int T>
__global__ __launch_bounds__(T, 1) void fps4_kernel(const float* __restrict__ xyz,
                                                    float* __restrict__ nx) {
  static_assert(N == 4 * T, "fps4: need exactly 4 points per thread");
  constexpr int W = T / 64;
  __shared__ float4 sslot[2][W][2];
  __shared__ int fid[NP];
  int b = blockIdx.x, t = threadIdx.x;
  int w = t >> 6;
  const float* base = xyz + (size_t)b * 3 * N;
  float4 px0, py0, pz0, dd0;
  FPS_LD4(px0, base, t);
  FPS_LD4(py0, base + N, t);
  FPS_LD4(pz0, base + 2 * N, t);
  dd0 = make_float4(1e10f, 1e10f, 1e10f, 1e10f);
  if (t == 0) {
    fid[0] = 0;
    unsigned long long k0 = ~0ull;
    sslot[0][0][0] = make_float4(__uint_as_float((unsigned)k0),
                                 __uint_as_float((unsigned)(k0 >> 32)), px0.x, py0.x);
    sslot[0][0][1] = make_float4(pz0.x, 0.0f, 0.0f, 0.0f);
  }
  if (t >= 64 && (t & 63) == 0) {
    sslot[0][w][0] = make_float4(0.0f, 0.0f, 0.0f, 0.0f);
    sslot[0][w][1] = make_float4(0.0f, 0.0f, 0.0f, 0.0f);
  }
  int par = 0;
  __syncthreads();
  for (int it = 1; it < NP; ++it) {
    float4 q0 = sslot[par][0][0];
    float4 q1 = sslot[par][0][1];
    unsigned long long mk =
        ((unsigned long long)__float_as_uint(q0.y) << 32) | __float_as_uint(q0.x);
    float cx = q0.z, cy = q0.w, cz = q1.x;
#pragma unroll
    for (int w2 = 1; w2 < W; ++w2) {
      float4 p0 = sslot[par][w2][0];
      float4 p1 = sslot[par][w2][1];
      unsigned long long k2 =
          ((unsigned long long)__float_as_uint(p0.y) << 32) | __float_as_uint(p0.x);
      if (k2 > mk) { mk = k2; cx = p0.z; cy = p0.w; cz = p1.x; }
    }
    if (t == 0) fid[it - 1] = (int)(~(unsigned)mk);
    float bestf = -1.0f;
    int besti = t;
    float bx = px0.x, by = py0.x, bz = pz0.x;
    FPS_STEP(0, x, 0) FPS_STEP(0, y, T) FPS_STEP(0, z, 2 * T) FPS_STEP(0, w, 3 * T)
    float wmax = wave_max_f32_nonneg(bestf);
    if (fps_pub_lane(bestf, wmax, besti)) {
      unsigned long long key =
          ((unsigned long long)__float_as_uint(wmax) << 32) | (unsigned)(~besti);
      sslot[par ^ 1][w][0] = make_float4(__uint_as_float((unsigned)key),
                                         __uint_as_float((unsigned)(key >> 32)), bx, by);
      sslot[par ^ 1][w][1] = make_float4(bz, 0.0f, 0.0f, 0.0f);
    }
    __syncthreads();
    par ^= 1;
  }
  {
    float4 q0 = sslot[par][0][0];
    unsigned long long mk =
        ((unsigned long long)__float_as_uint(q0.y) << 32) | __float_as_uint(q0.x);
#pragma unroll
    for (int w2 = 1; w2 < W; ++w2) {
      float4 p0 = sslot[par][w2][0];
      unsigned long long k2 =
          ((unsigned long long)__float_as_uint(p0.y) << 32) | __float_as_uint(p0.x);
      if (k2 > mk) mk = k2;
    }
    if (t == 0) fid[NP - 1] = (int)(~(unsigned)mk);
  }
  __syncthreads();
  for (int s = t; s < NP; s += T) {
    int f = fid[s];
    nx[(size_t)b * 3 * NP + s] = base[f];
    nx[(size_t)b * 3 * NP + NP + s] = base[N + f];
    nx[(size_t)b * 3 * NP + 2 * NP + s] = base[2 * N + f];
  }
}

// ---------------- ball query ----------------
template <int NPTS, int NQ, int NS>
__global__ void bq_kernel(const float* __restrict__ pts, const float* __restrict__ qry,
                          float r2, int* __restrict__ gidx) {
  int gw = (blockIdx.x * blockDim.x + threadIdx.x) >> 6;
  int lane = threadIdx.x & 63;
  if (gw >= kB * NQ) return;
  int b = gw / NQ, s = gw - b * NQ;
  const float* pb = pts + (size_t)b * 3 * NPTS;
  float cx = qry[(size_t)b * 3 * NQ + s];
  float cy = qry[(size_t)b * 3 * NQ + NQ + s];
  float cz = qry[(size_t)b * 3 * NQ + 2 * NQ + s];
  float ss = fmaf(cz, cz, fmaf(cy, cy, __fmul_rn(cx, cx)));
  int* out = gidx + (size_t)gw * NS;
  int have = 0, first = 0;
  bool gotfirst = false;
  for (int n0 = 0; n0 < NPTS; n0 += 64) {
    int n = n0 + lane;
    float x = pb[n], y = pb[NPTS + n], z = pb[2 * NPTS + n];
    float dd = fmaf(z, z, fmaf(y, y, __fmul_rn(x, x)));
    float cross = fmaf(cz, z, fmaf(cy, y, __fmul_rn(cx, x)));
    float sqr = __fsub_rn(__fadd_rn(ss, dd), __fmul_rn(2.0f, cross));
    bool pred = !(sqr > r2);
    unsigned long long mask = __ballot(pred);
    if (!gotfirst && mask) { first = n0 + (__ffsll(mask) - 1); gotfirst = true; }
    if (pred) {
      int pos = have + __popcll(mask & ((1ull << lane) - 1ull));
      if (pos < NS) out[pos] = n;
    }
    have += __popcll(mask);
    if (have >= NS) break;
  }
  for (int slot = have + lane; slot < NS; slot += 64) out[slot] = first;
}

// ---------------- SA1 grouped MLP (3->64->64->128) + max over 32 samples ----------------
__global__ __launch_bounds__(256, 2) void sa1_mlp_kernel(
    const float* __restrict__ xyz, const float* __restrict__ nx1,
    const int* __restrict__ gidx,
    const float* __restrict__ W0f, const float* __restrict__ bf0,   // [64][4], [64]
    const float* __restrict__ WT1, const float* __restrict__ bf1,   // [64][64]
    const float* __restrict__ WT2, const float* __restrict__ bf2,   // [64][128]
    float* __restrict__ l1_pts) {
  __shared__ float XT[64 * 256];   // reused for X1 then X2
  int t = threadIdx.x;
  int qi = t >> 5, sm = t & 31;
  int q = blockIdx.x * 8 + qi;
  int b = q >> 9, s = q & 511;
  int idx = gidx[(size_t)q * kNS1 + sm];
  float cx = nx1[b * 1536 + s];
  float cy = nx1[b * 1536 + 512 + s];
  float cz = nx1[b * 1536 + 1024 + s];
  const float* pb = xyz + (size_t)b * 3 * kN1;
  float f0 = pb[idx] - cx, f1 = pb[kN1 + idx] - cy, f2 = pb[2 * kN1 + idx] - cz;
  for (int j = 0; j < 64; ++j) {
    float4 w = *(const float4*)&W0f[j * 4];
    float v = fmaf(f2, w.z, fmaf(f1, w.y, fmaf(f0, w.x, bf0[j])));
    XT[j * 256 + t] = fmaxf(v, 0.0f);
  }
  __syncthreads();
  float acc[64];
#pragma unroll
  for (int j = 0; j < 64; ++j) acc[j] = bf1[j];
  for (int k = 0; k < 64; ++k) {
    float xk = XT[k * 256 + t];
    const float* wr = WT1 + k * 64;
#pragma unroll
    for (int j = 0; j < 64; ++j) acc[j] = fmaf(xk, wr[j], acc[j]);
  }
  __syncthreads();
#pragma unroll
  for (int j = 0; j < 64; ++j) XT[j * 256 + t] = fmaxf(acc[j], 0.0f);
  __syncthreads();
  float* outp = l1_pts + (size_t)q * 128;
  for (int jp = 0; jp < 2; ++jp) {
#pragma unroll
    for (int j = 0; j < 64; ++j) acc[j] = bf2[jp * 64 + j];
    for (int k = 0; k < 64; ++k) {
      float xk = XT[k * 256 + t];
      const float* wr = WT2 + k * 128 + jp * 64;
#pragma unroll
      for (int j = 0; j < 64; ++j) acc[j] = fmaf(xk, wr[j], acc[j]);
    }
#pragma unroll
    for (int j = 0; j < 64; ++j) {
      float m = fmaxf(acc[j], 0.0f);
      m = fmaxf(m, __shfl_xor(m, 1, 64));
      m = fmaxf(m, __shfl_xor(m, 2, 64));
      m = fmaxf(m, __shfl_xor(m, 4, 64));
      m = fmaxf(m, __shfl_xor(m, 8, 64));
      m = fmaxf(m, __shfl_xor(m, 16, 64));
      if (sm == 0) outp[jp * 64 + j] = m;
    }
  }
}

// ---------------- SA2 grouped MLP (131->128->128->256) + max over 64 samples ----------------
#define F_STR 133
__global__ __launch_bounds__(256, 4) void sa2_mlp_kernel(
    const float* __restrict__ nx1, const float* __restrict__ l1_pts,
    const float* __restrict__ nx2, const int* __restrict__ gidx2,
    const float* __restrict__ WT1, const float* __restrict__ bf1,   // [132][128]
    const float* __restrict__ WT2, const float* __restrict__ bf2,   // [128][128]
    const float* __restrict__ WT3, const float* __restrict__ bf3,   // [128][256]
    float* __restrict__ l2_pts) {
  __shared__ float fb[64 * F_STR];
  int t = threadIdx.x;
  int lane = t & 63;
  int wg = __builtin_amdgcn_readfirstlane(t >> 6);
  int q = blockIdx.x;
  int b = q >> 7, s = q & 127;
  int idx = gidx2[(size_t)q * kNS2 + lane];
  const float* pr = l1_pts + ((size_t)(b * kS1) + idx) * 128;
  float* frow = fb + lane * F_STR;
#pragma unroll
  for (int i = 0; i < 8; ++i) {
    float4 v = *(const float4*)&pr[wg * 32 + i * 4];
    frow[3 + wg * 32 + i * 4 + 0] = v.x;
    frow[3 + wg * 32 + i * 4 + 1] = v.y;
    frow[3 + wg * 32 + i * 4 + 2] = v.z;
    frow[3 + wg * 32 + i * 4 + 3] = v.w;
  }
  if (wg == 0) {
    float cx = nx2[b * 384 + s];
    float cy = nx2[b * 384 + 128 + s];
    float cz = nx2[b * 384 + 256 + s];
    frow[0] = nx1[b * 1536 + idx] - cx;
    frow[1] = nx1[b * 1536 + 512 + idx] - cy;
    frow[2] = nx1[b * 1536 + 1024 + idx] - cz;
    frow[131] = 0.0f;
  }
  __syncthreads();
  float acc[32];
#pragma unroll
  for (int j = 0; j < 32; ++j) acc[j] = bf1[wg * 32 + j];
  for (int k = 0; k < 132; k += 2) {   // chunk-2: both rows + both xk issued first
    float x0 = frow[k];
    float x1 = frow[k + 1];
    const float* w0 = WT1 + k * 128 + wg * 32;
    const float* w1 = WT1 + (k + 1) * 128 + wg * 32;
#pragma unroll
    for (int j = 0; j < 32; ++j) acc[j] = fmaf(x0, w0[j], acc[j]);
#pragma unroll
    for (int j = 0; j < 32; ++j) acc[j] = fmaf(x1, w1[j], acc[j]);
  }
  __syncthreads();
#pragma unroll
  for (int j = 0; j < 32; ++j) frow[wg * 32 + j] = fmaxf(acc[j], 0.0f);
  __syncthreads();
#pragma unroll
  for (int j = 0; j < 32; ++j) acc[j] = bf2[wg * 32 + j];
  for (int k = 0; k < 128; k += 2) {
    float x0 = frow[k];
    float x1 = frow[k + 1];
    const float* w0 = WT2 + k * 128 + wg * 32;
    const float* w1 = WT2 + (k + 1) * 128 + wg * 32;
#pragma unroll
    for (int j = 0; j < 32; ++j) acc[j] = fmaf(x0, w0[j], acc[j]);
#pragma unroll
    for (int j = 0; j < 32; ++j) acc[j] = fmaf(x1, w1[j], acc[j]);
  }
  __syncthreads();
#pragma unroll
  for (int j = 0; j < 32; ++j) frow[wg * 32 + j] = fmaxf(acc[j], 0.0f);
  __syncthreads();
  float* outp = l2_pts + (size_t)q * 256;
  for (int jp = 0; jp < 2; ++jp) {
    int j0 = wg * 64 + jp * 32;
#pragma unroll
    for (int j = 0; j < 32; ++j) acc[j] = bf3[j0 + j];
    for (int k = 0; k < 128; k += 2) {
      float x0 = frow[k];
      float x1 = frow[k + 1];
      const float* w0 = WT3 + k * 256 + j0;
      const float* w1 = WT3 + (k + 1) * 256 + j0;
#pragma unroll
      for (int j = 0; j < 32; ++j) acc[j] = fmaf(x0, w0[j], acc[j]);
#pragma unroll
      for (int j = 0; j < 32; ++j) acc[j] = fmaf(x1, w1[j], acc[j]);
    }
#pragma unroll
    for (int j = 0; j < 32; ++j) {
      float m = fmaxf(acc[j], 0.0f);
      m = fmaxf(m, __shfl_xor(m, 1, 64));
      m = fmaxf(m, __shfl_xor(m, 2, 64));
      m = fmaxf(m, __shfl_xor(m, 4, 64));
      m = fmaxf(m, __shfl_xor(m, 8, 64));
      m = fmaxf(m, __shfl_xor(m, 16, 64));
      m = fmaxf(m, __shfl_xor(m, 32, 64));
      if (lane == 0) outp[j0 + j] = m;
    }
  }
}

// ---------------- SA3 (group-all): 259->256->512->1024 -> max over 128 ----------------
__global__ __launch_bounds__(256, 2) void sa3_passA_kernel(
    const float* __restrict__ nx2, const float* __restrict__ l2_pts,
    const float* __restrict__ WT, const float* __restrict__ bf,
    float* __restrict__ Y) {   // O = 256
  __shared__ float sF[16 * 260];
  int stile = blockIdx.x, t = threadIdx.x;
  int j = t;
  for (int i = t; i < 16 * 260; i += 256) {
    int row = stile * 16 + i / 260, k = i - (i / 260) * 260;
    int b = row >> 7, s = row & 127;
    float v;
    if (k < 3) v = nx2[b * 384 + k * 128 + s];
    else if (k < 259) v = l2_pts[(size_t)row * 256 + (k - 3)];
    else v = 0.0f;
    sF[i] = v;
  }
  __syncthreads();
  float acc[16];
  float bj = bf[j];
#pragma unroll
  for (int s = 0; s < 16; ++s) acc[s] = bj;
  for (int k = 0; k < 260; k += 4) {
    float w0 = WT[(size_t)k * 256 + j];
    float w1 = WT[(size_t)(k + 1) * 256 + j];
    float w2 = WT[(size_t)(k + 2) * 256 + j];
    float w3 = WT[(size_t)(k + 3) * 256 + j];
#pragma unroll
    for (int s = 0; s < 16; ++s) {
      const float4 fv = *(const float4*)&sF[s * 260 + k];
      acc[s] = fmaf(fv.x, w0, acc[s]);
      acc[s] = fmaf(fv.y, w1, acc[s]);
      acc[s] = fmaf(fv.z, w2, acc[s]);
      acc[s] = fmaf(fv.w, w3, acc[s]);
    }
  }
  float* yb = Y + (size_t)stile * 16 * 256 + j;
#pragma unroll
  for (int s = 0; s < 16; ++s) yb[(size_t)s * 256] = fmaxf(acc[s], 0.0f);
}

template <int KP>
__global__ __launch_bounds__(256, 2) void mlp_pass_kernel(
    const float* __restrict__ X, const float* __restrict__ WT, const float* __restrict__ bf,
    int O, float* __restrict__ Y) {
  __shared__ float sF[16 * KP];
  int stile = blockIdx.x, t = threadIdx.x;
  int j = blockIdx.y * 256 + t;
  const float* xb = X + (size_t)stile * 16 * KP;
  for (int i = t; i < 16 * KP; i += 256) sF[i] = xb[i];
  __syncthreads();
  float acc[16];
  float bj = bf[j];
#pragma unroll
  for (int s = 0; s < 16; ++s) acc[s] = bj;
  for (int k = 0; k < KP; k += 4) {
    float w0 = WT[(size_t)k * O + j];
    float w1 = WT[(size_t)(k + 1) * O + j];
    float w2 = WT[(size_t)(k + 2) * O + j];
    float w3 = WT[(size_t)(k + 3) * O + j];
#pragma unroll
    for (int s = 0; s < 16; ++s) {
      const float4 fv = *(const float4*)&sF[s * KP + k];
      acc[s] = fmaf(fv.x, w0, acc[s]);
      acc[s] = fmaf(fv.y, w1, acc[s]);
      acc[s] = fmaf(fv.z, w2, acc[s]);
      acc[s] = fmaf(fv.w, w3, acc[s]);
    }
  }
  float* yb = Y + (size_t)stile * 16 * O + j;
#pragma unroll
  for (int s = 0; s < 16; ++s) yb[(size_t)s * O] = fmaxf(acc[s], 0.0f);
}

__global__ __launch_bounds__(256, 2) void sa3_final_kernel(
    const float* __restrict__ X2g, const float* __restrict__ WTc, const float* __restrict__ bfc,
    float* __restrict__ out) {
  __shared__ float sF[16 * 512];
  int b = blockIdx.x, t = threadIdx.x;
  int j = blockIdx.y * 256 + t;
  float m = 0.0f;
  float bj = bfc[j];
  for (int st = 0; st < 8; ++st) {
    const float* xb = X2g + ((size_t)b * 128 + st * 16) * 512;
    for (int i = t; i < 16 * 512; i += 256) sF[i] = xb[i];
    __syncthreads();
    float acc[16];
#pragma unroll
    for (int s = 0; s < 16; ++s) acc[s] = bj;
    for (int k = 0; k < 512; k += 4) {
      float w0 = WTc[(size_t)k * 1024 + j];
      float w1 = WTc[(size_t)(k + 1) * 1024 + j];
      float w2 = WTc[(size_t)(k + 2) * 1024 + j];
      float w3 = WTc[(size_t)(k + 3) * 1024 + j];
#pragma unroll
      for (int s = 0; s < 16; ++s) {
        const float4 fv = *(const float4*)&sF[s * 512 + k];
        acc[s] = fmaf(fv.x, w0, acc[s]);
        acc[s] = fmaf(fv.y, w1, acc[s]);
        acc[s] = fmaf(fv.z, w2, acc[s]);
        acc[s] = fmaf(fv.w, w3, acc[s]);
      }
    }
#pragma unroll
    for (int s = 0; s < 16; ++s) m = fmaxf(m, fmaxf(acc[s], 0.0f));
    __syncthreads();
  }
  out[(size_t)b * 1024 + j] = m;
}

// ---------------- launch ----------------
extern "C" void kernel_launch(void* const* d_in, const int* in_sizes, int n_in,
                              void* d_out, int out_size, void* d_ws, size_t ws_size,
                              hipStream_t stream) {
  (void)in_sizes; (void)n_in; (void)out_size; (void)ws_size;
  const float* xyz = (const float*)d_in[0];
  auto WP = [&](int layer, int part) -> const float* {
    return (const float*)d_in[1 + layer * 4 + part];
  };
  float* wsf = (float*)d_ws;
  size_t cur = 0;
  auto alloc = [&](size_t n) { size_t o = cur; cur += (n + 63) & ~(size_t)63; return o; };
  size_t o_nx1 = alloc((size_t)kB * 3 * kS1);
  size_t o_nx2 = alloc((size_t)kB * 3 * kS2);
  size_t o_l1pts = alloc((size_t)kB * kS1 * 128);
  size_t o_l2pts = alloc((size_t)kB * kS2 * 256);
  size_t o_X1g = alloc((size_t)kB * kS2 * 256);
  size_t o_X2g = alloc((size_t)kB * kS2 * 512);
  size_t o_s1w0 = alloc(64 * 4), o_s1b0 = alloc(64);
  size_t o_s1w1 = alloc(64 * 64), o_s1b1 = alloc(64);
  size_t o_s1wt2 = alloc(64 * 128), o_s1b2 = alloc(128);
  size_t o_s2w1 = alloc(132 * 128), o_s2b1 = alloc(128);
  size_t o_s2wt2 = alloc(128 * 128), o_s2b2 = alloc(128);
  size_t o_s2w3 = alloc(128 * 256), o_s2b3 = alloc(256);
  size_t o_s3wtA = alloc(260 * 256), o_s3bA = alloc(256);
  size_t o_s3wtB = alloc(256 * 512), o_s3bB = alloc(512);
  size_t o_s3wtC = alloc(512 * 1024), o_s3bC = alloc(1024);
  size_t o_gidx1 = alloc((size_t)kB * kS1 * kNS1);
  size_t o_gidx2 = alloc((size_t)kB * kS2 * kNS2);
  int* gidx1 = (int*)(wsf + o_gidx1);
  int* gidx2 = (int*)(wsf + o_gidx2);

  // fused fold of all 9 layers
  FoldPack fp;
  const int OKKp[9][3] = {{64, 3, 4},     {64, 64, 64},   {128, 64, 64},
                          {128, 131, 132}, {128, 128, 128}, {256, 128, 128},
                          {256, 259, 260}, {512, 256, 256}, {1024, 512, 512}};
  float* wouts[9] = {wsf + o_s1w0, wsf + o_s1w1, wsf + o_s1wt2,
                     wsf + o_s2w1, wsf + o_s2wt2, wsf + o_s2w3,
                     wsf + o_s3wtA, wsf + o_s3wtB, wsf + o_s3wtC};
  float* bouts[9] = {wsf + o_s1b0, wsf + o_s1b1, wsf + o_s1b2,
                     wsf + o_s2b1, wsf + o_s2b2, wsf + o_s2b3,
                     wsf + o_s3bA, wsf + o_s3bB, wsf + o_s3bC};
  const int nblk[9] = {1, 4, 8, 17, 16, 32, 65, 128, 512};
  fp.cum[0] = 0;
  for (int L = 0; L < 9; ++L) {
    fp.d[L].W = WP(L, 0);
    fp.d[L].b = WP(L, 1);
    fp.d[L].g = WP(L, 2);
    fp.d[L].bt = WP(L, 3);
    fp.d[L].Wout = wouts[L];
    fp.d[L].bout = bouts[L];
    fp.d[L].O = OKKp[L][0];
    fp.d[L].K = OKKp[L][1];
    fp.d[L].Kp = OKKp[L][2];
    fp.d[L].transposed = (L == 0) ? 0 : 1;
    fp.cum[L + 1] = fp.cum[L] + nblk[L];
  }
  foldall_kernel<<<fp.cum[9], 256, 0, stream>>>(fp);

  // SA1
  fps16_kernel<kN1, kS1, 256><<<kB, 256, 0, stream>>>(xyz, wsf + o_nx1);
  bq_kernel<kN1, kS1, kNS1><<<(kB * kS1) / 4, 256, 0, stream>>>(xyz, wsf + o_nx1, 0.04f, gidx1);
  sa1_mlp_kernel<<<(kB * kS1) / 8, 256, 0, stream>>>(
      xyz, wsf + o_nx1, gidx1,
      wsf + o_s1w0, wsf + o_s1b0, wsf + o_s1w1, wsf + o_s1b1, wsf + o_s1wt2, wsf + o_s1b2,
      wsf + o_l1pts);

  // SA2
  fps4_kernel<kS1, kS2, 128><<<kB, 128, 0, stream>>>(wsf + o_nx1, wsf + o_nx2);
  bq_kernel<kS1, kS2, kNS2><<<(kB * kS2) / 4, 256, 0, stream>>>(wsf + o_nx1, wsf + o_nx2, 0.16f, gidx2);
  sa2_mlp_kernel<<<kB * kS2, 256, 0, stream>>>(
      wsf + o_nx1, wsf + o_l1pts, wsf + o_nx2, gidx2,
      wsf + o_s2w1, wsf + o_s2b1, wsf + o_s2wt2, wsf + o_s2b2, wsf + o_s2w3, wsf + o_s2b3,
      wsf + o_l2pts);

  // SA3 (group all)
  sa3_passA_kernel<<<256, 256, 0, stream>>>(wsf + o_nx2, wsf + o_l2pts,
                                            wsf + o_s3wtA, wsf + o_s3bA, wsf + o_X1g);
  mlp_pass_kernel<256><<<dim3(256, 2), 256, 0, stream>>>(wsf + o_X1g, wsf + o_s3wtB, wsf + o_s3bB, 512, wsf + o_X2g);
  sa3_final_kernel<<<dim3(kB, 4), 256, 0, stream>>>(wsf + o_X2g, wsf + o_s3wtC, wsf + o_s3bC, (float*)d_out);
}